// Round 2
// baseline (94474.878 us; speedup 1.0000x reference)
//
#include <hip/hip_runtime.h>
#include <hip/hip_bf16.h>
#include <math.h>

// Problem constants
constexpr int L    = 1024;
constexpr int B    = 64;
constexpr int H    = 512;
constexpr int ED   = 512;
constexpr int PSSM = 21;
constexpr int DIN  = ED + PSSM;    // 533
constexpr int LU   = 60;
constexpr int NWG_DIR = 128;       // workgroups per direction
constexpr int JPW  = H / NWG_DIR;  // hidden units per WG = 4
constexpr int HB   = H * B;        // 32768

// ---------------------------------------------------------------------------
// P0: E2[dir][s][col] = sum_{k<512} embed[s][k] * Wih_dir[col][k]
// (the embedding half of the input GEMM only has 20 distinct rows)
// ---------------------------------------------------------------------------
__global__ __launch_bounds__(256) void prep_e2(
    const float* __restrict__ Wih_f, const float* __restrict__ Wih_b,
    const float* __restrict__ embed, float* __restrict__ E2)
{
    int idx  = blockIdx.x * 256 + threadIdx.x;   // 0 .. 81919
    int col  = idx & 2047;
    int rest = idx >> 11;                        // dir*20 + s
    int s    = rest % 20;
    int dir  = rest / 20;
    const float* W  = dir ? Wih_b : Wih_f;
    const float* er = embed + (size_t)s * ED;    // wave-uniform row
    const float* wr = W + (size_t)col * DIN;
    float a = 0.f;
    #pragma unroll 8
    for (int k = 0; k < ED; ++k) a = fmaf(er[k], wr[k], a);
    E2[idx] = a;
}

// ---------------------------------------------------------------------------
// P1: pssm_t[t][kk][b] = pssm[t][b][kk]   (coalesced reads in the LSTM loop)
// ---------------------------------------------------------------------------
__global__ void prep_pssm_t(const float* __restrict__ pssm, float* __restrict__ pt)
{
    int t = blockIdx.x, b = threadIdx.x;   // 64 threads
    for (int kk = 0; kk < PSSM; ++kk)
        pt[((size_t)t * PSSM + kk) * B + b] = pssm[((size_t)t * B + b) * PSSM + kk];
}

// ---------------------------------------------------------------------------
// K1: persistent bidirectional LSTM. 256 WGs (128 fwd + 128 bwd). 134 KB of
// static LDS forces exactly 1 WG/CU -> all 256 blocks co-resident on the 256
// CUs without a cooperative launch. Each WG owns 4 hidden units (16 gate rows).
// fp32 h lives in a 2-slot ring (recurrence, exact); bf16 h history is stored
// for the projection kernel.
// Per step: cheap input part (E2 gather + 21 pssm FMAs) -> spin on flags ->
// stage h ring slot into LDS -> K=512 FMA loop -> gates -> publish.
// ---------------------------------------------------------------------------
__global__ __launch_bounds__(256) void lstm_persistent(
    const float* __restrict__ E2, const float* __restrict__ pt,
    const int* __restrict__ seq,
    const float* __restrict__ Wih_f, const float* __restrict__ Whh_f,
    const float* __restrict__ bih_f, const float* __restrict__ bhh_f,
    const float* __restrict__ Wih_b, const float* __restrict__ Whh_b,
    const float* __restrict__ bih_b, const float* __restrict__ bhh_b,
    float* __restrict__ hr,                    // [2 dir][2 slot][H][B]
    __hip_bfloat16* __restrict__ hs16_f,
    __hip_bfloat16* __restrict__ hs16_b,
    int* __restrict__ flags)                   // [2][128]
{
    __shared__ float hsh[H][B];                // 128 KB staged h_{prev}
    __shared__ float zsh[4][JPW][B];           // 4 KB gate pre-activations
    __shared__ float csh[JPW][B];              // 1 KB cell state
    __shared__ float wpsh[4][JPW][PSSM];       // 1.3 KB pssm weight slice

    const int wg    = blockIdx.x;
    const int dir   = wg >> 7;                 // 0 fwd, 1 bwd
    const int wslot = wg & 127;
    const int j0    = wslot * JPW;
    const int tid   = threadIdx.x;
    const int b     = tid & 63;
    const int g     = __builtin_amdgcn_readfirstlane(tid >> 6); // gate 0..3

    const float* Wih = dir ? Wih_b : Wih_f;
    const float* Whh = dir ? Whh_b : Whh_f;
    const float* bih = dir ? bih_b : bih_f;
    const float* bhh = dir ? bhh_b : bhh_f;
    float*      ring = hr + (size_t)dir * 2 * HB;
    __hip_bfloat16* hs16 = dir ? hs16_b : hs16_f;
    int*         flg = flags + dir * 128;

    // fill pssm-weight slice + cell init
    for (int i = tid; i < 4 * JPW * PSSM; i += 256) {
        int gg = i / (JPW * PSSM), rem = i % (JPW * PSSM);
        int jj = rem / PSSM, kk = rem % PSSM;
        int col = gg * H + j0 + jj;
        wpsh[gg][jj][kk] = Wih[(size_t)col * DIN + ED + kk];
    }
    csh[tid >> 6][tid & 63] = 0.f;

    // wave-uniform recurrent weight rows + bias
    const float* whhr[JPW];
    float bias[JPW];
    #pragma unroll
    for (int jj = 0; jj < JPW; ++jj) {
        int col = g * H + j0 + jj;
        whhr[jj] = Whh + (size_t)col * H;
        bias[jj] = bih[col] + bhh[col];
    }
    __syncthreads();

    int dead = 0;
    for (int s = 0; s < L; ++s) {
        const int t = dir ? (L - 1 - s) : s;

        // ---- input part (h-independent, overlaps other WGs' tails) ----
        float acc[JPW];
        int sb = seq[t * B + b];
        const float* e2r = E2 + ((size_t)(dir * 20 + sb) * 2048) + g * H + j0;
        #pragma unroll
        for (int jj = 0; jj < JPW; ++jj) acc[jj] = bias[jj] + e2r[jj];
        const float* ptr = pt + (size_t)t * PSSM * B + b;
        #pragma unroll
        for (int kk = 0; kk < PSSM; ++kk) {
            float pv = ptr[(size_t)kk * B];
            #pragma unroll
            for (int jj = 0; jj < JPW; ++jj)
                acc[jj] = fmaf(pv, wpsh[g][jj][kk], acc[jj]);
        }

        // ---- wait for all WGs of this direction to publish step s-1 ----
        if (s > 0 && !dead) {
            int it = 0;
            while (__hip_atomic_load(&flg[tid & 127], __ATOMIC_ACQUIRE,
                                     __HIP_MEMORY_SCOPE_AGENT) < s) {
                __builtin_amdgcn_s_sleep(2);
                if (++it > (1 << 18)) { dead = 1; break; }   // anti-hang
            }
        }
        __syncthreads();
        __threadfence();   // acquire: drop stale cached copies of the ring

        // ---- stage h_{prev} ring slot (128 KB) into LDS ----
        {
            const float4* hp4 = (const float4*)(ring + (size_t)((s + 1) & 1) * HB);
            float4* ls4 = (float4*)&hsh[0][0];
            #pragma unroll 8
            for (int it = 0; it < 32; ++it)
                ls4[tid + it * 256] = hp4[tid + it * 256];
        }
        __syncthreads();

        // ---- recurrent GEMM part: K = 512 ----
        #pragma unroll 8
        for (int k = 0; k < H; ++k) {
            float hv = hsh[k][b];
            #pragma unroll
            for (int jj = 0; jj < JPW; ++jj)
                acc[jj] = fmaf(hv, whhr[jj][k], acc[jj]);   // weight: scalar load
        }
        #pragma unroll
        for (int jj = 0; jj < JPW; ++jj) zsh[g][jj][b] = acc[jj];
        __syncthreads();

        // ---- gates: thread (jj, b) combines the 4 gate values ----
        {
            const int jj = tid >> 6;
            float iv = zsh[0][jj][b], fv = zsh[1][jj][b];
            float gv = zsh[2][jj][b], ov = zsh[3][jj][b];
            iv = 1.f / (1.f + __expf(-iv));
            fv = 1.f / (1.f + __expf(-fv));
            gv = tanhf(gv);
            ov = 1.f / (1.f + __expf(-ov));
            float c = fv * csh[jj][b] + iv * gv;
            csh[jj][b] = c;
            float hv = ov * tanhf(c);
            ring[(size_t)(s & 1) * HB + (size_t)(j0 + jj) * B + b] = hv;
            hs16[(size_t)t * HB + (size_t)(j0 + jj) * B + b] = __float2bfloat16(hv);
        }
        __threadfence();   // release: push h to device scope
        __syncthreads();   // all lanes' stores + fences done
        if (tid == 0)
            __hip_atomic_store(&flg[wslot], s + 1, __ATOMIC_RELEASE,
                               __HIP_MEMORY_SCOPE_AGENT);
    }
}

// ---------------------------------------------------------------------------
// K2: logits -> softmax -> alphabet mix -> normalized sin/cos of torsions.
// (atan2 unnecessary: geometry only needs sin/cos, and the softmax
// denominator cancels under normalization.)
// ---------------------------------------------------------------------------
__global__ __launch_bounds__(256) void proj_softmax(
    const __hip_bfloat16* __restrict__ hs16_f, const __hip_bfloat16* __restrict__ hs16_b,
    const float* __restrict__ W_lin, const float* __restrict__ b_lin,
    const float* __restrict__ alphabet, float* __restrict__ sp, float* __restrict__ cp)
{
    const int t   = blockIdx.x;
    const int tid = threadIdx.x;
    const int b   = tid & 63;
    const int ug  = __builtin_amdgcn_readfirstlane(tid >> 6);  // 0..3
    constexpr int NU = 15;                                     // 60 = 4*15

    __shared__ float lg[B][LU];
    __shared__ float sa[LU][3], ca[LU][3];
    if (tid < LU) {
        for (int k = 0; k < 3; ++k) {
            float a = alphabet[tid * 3 + k];
            sa[tid][k] = __sinf(a);
            ca[tid][k] = __cosf(a);
        }
    }

    const int u0 = ug * NU;
    float acc[NU];
    #pragma unroll
    for (int i = 0; i < NU; ++i) acc[i] = b_lin[u0 + i];

    const __hip_bfloat16* hf = hs16_f + (size_t)t * HB + b;
    const __hip_bfloat16* hb = hs16_b + (size_t)t * HB + b;
    #pragma unroll 4
    for (int j = 0; j < H; ++j) {
        float hv = __bfloat162float(hf[(size_t)j * B]);
        #pragma unroll
        for (int i = 0; i < NU; ++i)
            acc[i] = fmaf(hv, W_lin[(size_t)(u0 + i) * (2 * H) + j], acc[i]);
    }
    #pragma unroll 4
    for (int j = 0; j < H; ++j) {
        float hv = __bfloat162float(hb[(size_t)j * B]);
        #pragma unroll
        for (int i = 0; i < NU; ++i)
            acc[i] = fmaf(hv, W_lin[(size_t)(u0 + i) * (2 * H) + H + j], acc[i]);
    }
    #pragma unroll
    for (int i = 0; i < NU; ++i) lg[b][u0 + i] = acc[i];
    __syncthreads();

    if (tid < B) {
        float m = -1e30f;
        for (int u = 0; u < LU; ++u) m = fmaxf(m, lg[tid][u]);
        float sv[3] = {0, 0, 0}, cv[3] = {0, 0, 0};
        for (int u = 0; u < LU; ++u) {
            float e = __expf(lg[tid][u] - m);
            for (int k = 0; k < 3; ++k) {
                sv[k] = fmaf(e, sa[u][k], sv[k]);
                cv[k] = fmaf(e, ca[u][k], cv[k]);
            }
        }
        for (int k = 0; k < 3; ++k) {
            float r = rsqrtf(sv[k] * sv[k] + cv[k] * cv[k]);
            sp[((size_t)t * B + tid) * 3 + k] = sv[k] * r;
            cp[((size_t)t * B + tid) * 3 + k] = cv[k] * r;
        }
    }
}

// ---------------------------------------------------------------------------
// K3: sequential NeRF extension. One wave, lane = chain.
// ---------------------------------------------------------------------------
__global__ void geometry(const float* __restrict__ sp, const float* __restrict__ cp,
                         float* __restrict__ out)
{
    const int b = threadIdx.x;   // 64
    const float Rj[3] = {132.868f, 145.801f, 152.326f};
    const float Tj[3] = {2.028f, 2.124f, 1.941f};
    float cT[3], sT[3];
    for (int j = 0; j < 3; ++j) { cT[j] = cosf(Tj[j]); sT[j] = sinf(Tj[j]); }

    for (int r = 0; r < 3; ++r)
        for (int c = 0; c < 3; ++c)
            out[((size_t)r * B + b) * 3 + c] = (r == c) ? 1.f : 0.f;

    float Ax = 1.f, Ay = 0.f, Az = 0.f;
    float Bx = 0.f, By = 1.f, Bz = 0.f;
    float Cx = 0.f, Cy = 0.f, Cz = 1.f;

    for (int t = 0; t < L; ++t) {
        for (int j = 0; j < 3; ++j) {
            float sP = sp[((size_t)t * B + b) * 3 + j];
            float cP = cp[((size_t)t * B + b) * 3 + j];
            float d0 = -Rj[j] * cT[j];
            float d1 =  Rj[j] * cP * sT[j];
            float d2 =  Rj[j] * sP * sT[j];

            float bcx = Cx - Bx, bcy = Cy - By, bcz = Cz - Bz;
            float inv = rsqrtf(bcx * bcx + bcy * bcy + bcz * bcz);
            bcx *= inv; bcy *= inv; bcz *= inv;

            float abx = Bx - Ax, aby = By - Ay, abz = Bz - Az;
            float nx = aby * bcz - abz * bcy;
            float ny = abz * bcx - abx * bcz;
            float nz = abx * bcy - aby * bcx;
            inv = rsqrtf(nx * nx + ny * ny + nz * nz);
            nx *= inv; ny *= inv; nz *= inv;

            float mx = ny * bcz - nz * bcy;
            float my = nz * bcx - nx * bcz;
            float mz = nx * bcy - ny * bcx;

            float Dx = bcx * d0 + mx * d1 + nx * d2 + Cx;
            float Dy = bcy * d0 + my * d1 + ny * d2 + Cy;
            float Dz = bcz * d0 + mz * d1 + nz * d2 + Cz;

            size_t r = 3 + 3 * (size_t)t + j;
            out[(r * B + b) * 3 + 0] = Dx;
            out[(r * B + b) * 3 + 1] = Dy;
            out[(r * B + b) * 3 + 2] = Dz;

            Ax = Bx; Ay = By; Az = Bz;
            Bx = Cx; By = Cy; Bz = Cz;
            Cx = Dx; Cy = Dy; Cz = Dz;
        }
    }
}

// ---------------------------------------------------------------------------
extern "C" void kernel_launch(void* const* d_in, const int* in_sizes, int n_in,
                              void* d_out, int out_size, void* d_ws, size_t ws_size,
                              hipStream_t stream)
{
    const int*   seq      = (const int*)  d_in[0];
    const float* pssm     = (const float*)d_in[1];
    // d_in[2] = length (all full-length)
    const float* embed    = (const float*)d_in[3];
    const float* Wih_f    = (const float*)d_in[4];
    const float* Whh_f    = (const float*)d_in[5];
    const float* bih_f    = (const float*)d_in[6];
    const float* bhh_f    = (const float*)d_in[7];
    const float* Wih_b    = (const float*)d_in[8];
    const float* Whh_b    = (const float*)d_in[9];
    const float* bih_b    = (const float*)d_in[10];
    const float* bhh_b    = (const float*)d_in[11];
    const float* W_lin    = (const float*)d_in[12];
    const float* b_lin    = (const float*)d_in[13];
    const float* alphabet = (const float*)d_in[14];
    float* out = (float*)d_out;

    // workspace layout (~142 MB total)
    char* ws = (char*)d_ws;
    size_t off = 0;
    float* hr    = (float*)(ws + off); off += (size_t)4 * HB * 4;            // 512 KB
    int*   flags = (int*)  (ws + off); off += 256 * 4;                       // 1 KB (contiguous w/ hr)
    size_t zero_bytes = off;                                                 // one memset covers both
    float* E2    = (float*)(ws + off); off += (size_t)2 * 20 * 2048 * 4;     // 320 KB
    float* pt    = (float*)(ws + off); off += (size_t)L * PSSM * B * 4;      // 5.5 MB
    __hip_bfloat16* hs16_f = (__hip_bfloat16*)(ws + off); off += (size_t)L * HB * 2;  // 64 MB
    __hip_bfloat16* hs16_b = (__hip_bfloat16*)(ws + off); off += (size_t)L * HB * 2;  // 64 MB
    float* sp    = (float*)(ws + off); off += (size_t)L * B * 3 * 4;         // 768 KB
    float* cp    = (float*)(ws + off); off += (size_t)L * B * 3 * 4;         // 768 KB

    hipMemsetAsync(hr, 0, zero_bytes, stream);   // ring slots + flags

    prep_e2<<<dim3(320), dim3(256), 0, stream>>>(Wih_f, Wih_b, embed, E2);
    prep_pssm_t<<<dim3(L), dim3(64), 0, stream>>>(pssm, pt);

    lstm_persistent<<<dim3(2 * NWG_DIR), dim3(256), 0, stream>>>(
        E2, pt, seq, Wih_f, Whh_f, bih_f, bhh_f, Wih_b, Whh_b, bih_b, bhh_b,
        hr, hs16_f, hs16_b, flags);

    proj_softmax<<<dim3(L), dim3(256), 0, stream>>>(hs16_f, hs16_b, W_lin, b_lin,
                                                    alphabet, sp, cp);
    geometry<<<dim3(1), dim3(64), 0, stream>>>(sp, cp, out);
}

// Round 3
// 39333.698 us; speedup vs baseline: 2.4019x; 2.4019x over previous
//
#include <hip/hip_runtime.h>
#include <hip/hip_bf16.h>
#include <math.h>

// Problem constants
constexpr int L    = 1024;
constexpr int B    = 64;
constexpr int H    = 512;
constexpr int ED   = 512;
constexpr int PSSM = 21;
constexpr int DIN  = ED + PSSM;    // 533
constexpr int LU   = 60;
constexpr int NWG_DIR = 128;       // workgroups per direction
constexpr int JPW  = H / NWG_DIR;  // hidden units per WG = 4
constexpr int HB   = H * B;        // 32768

// ---------------------------------------------------------------------------
// P0: E2[dir][s][col] = sum_{k<512} embed[s][k] * Wih_dir[col][k]
// (the embedding half of the input GEMM only has 20 distinct rows)
// ---------------------------------------------------------------------------
__global__ __launch_bounds__(256) void prep_e2(
    const float* __restrict__ Wih_f, const float* __restrict__ Wih_b,
    const float* __restrict__ embed, float* __restrict__ E2)
{
    int idx  = blockIdx.x * 256 + threadIdx.x;   // 0 .. 81919
    int col  = idx & 2047;
    int rest = idx >> 11;                        // dir*20 + s
    int s    = rest % 20;
    int dir  = rest / 20;
    const float* W  = dir ? Wih_b : Wih_f;
    const float* er = embed + (size_t)s * ED;    // wave-uniform row
    const float* wr = W + (size_t)col * DIN;
    float a = 0.f;
    #pragma unroll 8
    for (int k = 0; k < ED; ++k) a = fmaf(er[k], wr[k], a);
    E2[idx] = a;
}

// ---------------------------------------------------------------------------
// P1: pssm_t[t][kk][b] = pssm[t][b][kk]   (coalesced reads in the LSTM loop)
// ---------------------------------------------------------------------------
__global__ void prep_pssm_t(const float* __restrict__ pssm, float* __restrict__ pt)
{
    int t = blockIdx.x, b = threadIdx.x;   // 64 threads
    for (int kk = 0; kk < PSSM; ++kk)
        pt[((size_t)t * PSSM + kk) * B + b] = pssm[((size_t)t * B + b) * PSSM + kk];
}

// ---------------------------------------------------------------------------
// K1: persistent bidirectional LSTM. 256 WGs (128 fwd + 128 bwd). ~136 KB of
// static LDS forces exactly 1 WG/CU -> all 256 blocks co-resident on 256 CUs.
// Each WG owns 4 hidden units (16 gate rows). fp32 h lives in a 2-slot ring
// (recurrence, exact); bf16 h history stored for the projection kernel.
//
// Sync per step (the R2 fix): tid0 polls ONE per-direction counter with an
// agent-scope ACQUIRE load (s_sleep backoff); everyone else waits at the
// barrier. Publish = barrier + tid0 RELEASE fetch_add. No explicit
// __threadfence: the acquire/release atomics carry the cache
// invalidate/writeback, once per WG per step instead of per-thread.
// ---------------------------------------------------------------------------
__global__ __launch_bounds__(256) void lstm_persistent(
    const float* __restrict__ E2, const float* __restrict__ pt,
    const int* __restrict__ seq,
    const float* __restrict__ Wih_f, const float* __restrict__ Whh_f,
    const float* __restrict__ bih_f, const float* __restrict__ bhh_f,
    const float* __restrict__ Wih_b, const float* __restrict__ Whh_b,
    const float* __restrict__ bih_b, const float* __restrict__ bhh_b,
    float* __restrict__ hr,                    // [2 dir][2 slot][H][B]
    __hip_bfloat16* __restrict__ hs16_f,
    __hip_bfloat16* __restrict__ hs16_b,
    int* __restrict__ cnt)                     // [2][L]
{
    __shared__ float hsh[H][B];                // 128 KB staged h_{prev}
    __shared__ float zsh[4][JPW][B];           // 4 KB gate pre-activations
    __shared__ float csh[JPW][B];              // 1 KB cell state
    __shared__ float wpsh[4][JPW][PSSM];       // 1.3 KB pssm weight slice
    __shared__ float wesh[20][17];             // 1.4 KB E2 slice (padded)

    const int wg    = blockIdx.x;
    const int dir   = wg >> 7;                 // 0 fwd, 1 bwd
    const int wslot = wg & 127;
    const int j0    = wslot * JPW;
    const int tid   = threadIdx.x;
    const int b     = tid & 63;
    const int g     = __builtin_amdgcn_readfirstlane(tid >> 6); // gate 0..3

    const float* Wih = dir ? Wih_b : Wih_f;
    const float* Whh = dir ? Whh_b : Whh_f;
    const float* bih = dir ? bih_b : bih_f;
    const float* bhh = dir ? bhh_b : bhh_f;
    float*      ring = hr + (size_t)dir * 2 * HB;
    __hip_bfloat16* hs16 = dir ? hs16_b : hs16_f;
    int*       mycnt = cnt + dir * L;

    // fill pssm-weight slice + E2 slice + cell init
    for (int i = tid; i < 4 * JPW * PSSM; i += 256) {
        int gg = i / (JPW * PSSM), rem = i % (JPW * PSSM);
        int jj = rem / PSSM, kk = rem % PSSM;
        int col = gg * H + j0 + jj;
        wpsh[gg][jj][kk] = Wih[(size_t)col * DIN + ED + kk];
    }
    for (int i = tid; i < 20 * 16; i += 256) {
        int s = i >> 4, c = i & 15;
        int col = (c / JPW) * H + j0 + (c % JPW);
        wesh[s][c] = E2[(size_t)(dir * 20 + s) * 2048 + col];
    }
    csh[tid >> 6][tid & 63] = 0.f;

    // wave-uniform recurrent weight rows + bias
    const float* whhr[JPW];
    float bias[JPW];
    #pragma unroll
    for (int jj = 0; jj < JPW; ++jj) {
        int col = g * H + j0 + jj;
        whhr[jj] = Whh + (size_t)col * H;
        bias[jj] = bih[col] + bhh[col];
    }
    __syncthreads();

    int dead = 0;
    for (int s = 0; s < L; ++s) {
        const int t = dir ? (L - 1 - s) : s;

        // ---- input part (h-independent, overlaps other WGs' tails) ----
        float acc[JPW];
        int sb = seq[t * B + b];
        #pragma unroll
        for (int jj = 0; jj < JPW; ++jj)
            acc[jj] = bias[jj] + wesh[sb][g * JPW + jj];
        const float* ptr = pt + (size_t)t * PSSM * B + b;
        #pragma unroll
        for (int kk = 0; kk < PSSM; ++kk) {
            float pv = ptr[(size_t)kk * B];
            #pragma unroll
            for (int jj = 0; jj < JPW; ++jj)
                acc[jj] = fmaf(pv, wpsh[g][jj][kk], acc[jj]);
        }

        // ---- wait: tid0 polls the step-(s-1) counter; others sit at barrier ----
        if (s > 0 && tid == 0 && !dead) {
            int it = 0;
            while (__hip_atomic_load(&mycnt[s - 1], __ATOMIC_ACQUIRE,
                                     __HIP_MEMORY_SCOPE_AGENT) < NWG_DIR) {
                __builtin_amdgcn_s_sleep(8);
                if (++it > (1 << 17)) { dead = 1; break; }   // anti-hang
            }
        }
        __syncthreads();   // releases waves after tid0's acquire (L1/L2 inv done)

        // ---- stage h_{prev} ring slot (128 KB) into LDS ----
        {
            const float4* hp4 = (const float4*)(ring + (size_t)((s + 1) & 1) * HB);
            float4* ls4 = (float4*)&hsh[0][0];
            #pragma unroll 8
            for (int it = 0; it < 32; ++it)
                ls4[tid + it * 256] = hp4[tid + it * 256];
        }
        __syncthreads();

        // ---- recurrent GEMM part: K = 512 ----
        #pragma unroll 8
        for (int k = 0; k < H; ++k) {
            float hv = hsh[k][b];
            #pragma unroll
            for (int jj = 0; jj < JPW; ++jj)
                acc[jj] = fmaf(hv, whhr[jj][k], acc[jj]);   // weight: scalar load
        }
        #pragma unroll
        for (int jj = 0; jj < JPW; ++jj) zsh[g][jj][b] = acc[jj];
        __syncthreads();

        // ---- gates: thread (jj, b) combines the 4 gate values ----
        {
            const int jj = tid >> 6;
            float iv = zsh[0][jj][b], fv = zsh[1][jj][b];
            float gv = zsh[2][jj][b], ov = zsh[3][jj][b];
            iv = 1.f / (1.f + __expf(-iv));
            fv = 1.f / (1.f + __expf(-fv));
            gv = tanhf(gv);
            ov = 1.f / (1.f + __expf(-ov));
            float c = fv * csh[jj][b] + iv * gv;
            csh[jj][b] = c;
            float hv = ov * tanhf(c);
            ring[(size_t)(s & 1) * HB + (size_t)(j0 + jj) * B + b] = hv;
            hs16[(size_t)t * HB + (size_t)(j0 + jj) * B + b] = __float2bfloat16(hv);
        }
        __syncthreads();   // all waves' stores drained (vmcnt0 before barrier)
        if (tid == 0)      // release RMW: wbl2 + counter bump, once per WG
            __hip_atomic_fetch_add(&mycnt[s], 1, __ATOMIC_RELEASE,
                                   __HIP_MEMORY_SCOPE_AGENT);
    }
}

// ---------------------------------------------------------------------------
// K2: logits -> softmax -> alphabet mix -> normalized sin/cos of torsions.
// (atan2 unnecessary: geometry only needs sin/cos, softmax denom cancels.)
// ---------------------------------------------------------------------------
__global__ __launch_bounds__(256) void proj_softmax(
    const __hip_bfloat16* __restrict__ hs16_f, const __hip_bfloat16* __restrict__ hs16_b,
    const float* __restrict__ W_lin, const float* __restrict__ b_lin,
    const float* __restrict__ alphabet, float* __restrict__ sp, float* __restrict__ cp)
{
    const int t   = blockIdx.x;
    const int tid = threadIdx.x;
    const int b   = tid & 63;
    const int ug  = __builtin_amdgcn_readfirstlane(tid >> 6);  // 0..3
    constexpr int NU = 15;                                     // 60 = 4*15

    __shared__ float lg[B][LU];
    __shared__ float sa[LU][3], ca[LU][3];
    if (tid < LU) {
        for (int k = 0; k < 3; ++k) {
            float a = alphabet[tid * 3 + k];
            sa[tid][k] = __sinf(a);
            ca[tid][k] = __cosf(a);
        }
    }

    const int u0 = ug * NU;
    float acc[NU];
    #pragma unroll
    for (int i = 0; i < NU; ++i) acc[i] = b_lin[u0 + i];

    const __hip_bfloat16* hf = hs16_f + (size_t)t * HB + b;
    const __hip_bfloat16* hb = hs16_b + (size_t)t * HB + b;
    #pragma unroll 4
    for (int j = 0; j < H; ++j) {
        float hv = __bfloat162float(hf[(size_t)j * B]);
        #pragma unroll
        for (int i = 0; i < NU; ++i)
            acc[i] = fmaf(hv, W_lin[(size_t)(u0 + i) * (2 * H) + j], acc[i]);
    }
    #pragma unroll 4
    for (int j = 0; j < H; ++j) {
        float hv = __bfloat162float(hb[(size_t)j * B]);
        #pragma unroll
        for (int i = 0; i < NU; ++i)
            acc[i] = fmaf(hv, W_lin[(size_t)(u0 + i) * (2 * H) + H + j], acc[i]);
    }
    #pragma unroll
    for (int i = 0; i < NU; ++i) lg[b][u0 + i] = acc[i];
    __syncthreads();

    if (tid < B) {
        float m = -1e30f;
        for (int u = 0; u < LU; ++u) m = fmaxf(m, lg[tid][u]);
        float sv[3] = {0, 0, 0}, cv[3] = {0, 0, 0};
        for (int u = 0; u < LU; ++u) {
            float e = __expf(lg[tid][u] - m);
            for (int k = 0; k < 3; ++k) {
                sv[k] = fmaf(e, sa[u][k], sv[k]);
                cv[k] = fmaf(e, ca[u][k], cv[k]);
            }
        }
        for (int k = 0; k < 3; ++k) {
            float r = rsqrtf(sv[k] * sv[k] + cv[k] * cv[k]);
            sp[((size_t)t * B + tid) * 3 + k] = sv[k] * r;
            cp[((size_t)t * B + tid) * 3 + k] = cv[k] * r;
        }
    }
}

// ---------------------------------------------------------------------------
// K3: sequential NeRF extension. One wave, lane = chain.
// ---------------------------------------------------------------------------
__global__ void geometry(const float* __restrict__ sp, const float* __restrict__ cp,
                         float* __restrict__ out)
{
    const int b = threadIdx.x;   // 64
    const float Rj[3] = {132.868f, 145.801f, 152.326f};
    const float Tj[3] = {2.028f, 2.124f, 1.941f};
    float cT[3], sT[3];
    for (int j = 0; j < 3; ++j) { cT[j] = cosf(Tj[j]); sT[j] = sinf(Tj[j]); }

    for (int r = 0; r < 3; ++r)
        for (int c = 0; c < 3; ++c)
            out[((size_t)r * B + b) * 3 + c] = (r == c) ? 1.f : 0.f;

    float Ax = 1.f, Ay = 0.f, Az = 0.f;
    float Bx = 0.f, By = 1.f, Bz = 0.f;
    float Cx = 0.f, Cy = 0.f, Cz = 1.f;

    for (int t = 0; t < L; ++t) {
        for (int j = 0; j < 3; ++j) {
            float sP = sp[((size_t)t * B + b) * 3 + j];
            float cP = cp[((size_t)t * B + b) * 3 + j];
            float d0 = -Rj[j] * cT[j];
            float d1 =  Rj[j] * cP * sT[j];
            float d2 =  Rj[j] * sP * sT[j];

            float bcx = Cx - Bx, bcy = Cy - By, bcz = Cz - Bz;
            float inv = rsqrtf(bcx * bcx + bcy * bcy + bcz * bcz);
            bcx *= inv; bcy *= inv; bcz *= inv;

            float abx = Bx - Ax, aby = By - Ay, abz = Bz - Az;
            float nx = aby * bcz - abz * bcy;
            float ny = abz * bcx - abx * bcz;
            float nz = abx * bcy - aby * bcx;
            inv = rsqrtf(nx * nx + ny * ny + nz * nz);
            nx *= inv; ny *= inv; nz *= inv;

            float mx = ny * bcz - nz * bcy;
            float my = nz * bcx - nx * bcz;
            float mz = nx * bcy - ny * bcx;

            float Dx = bcx * d0 + mx * d1 + nx * d2 + Cx;
            float Dy = bcy * d0 + my * d1 + ny * d2 + Cy;
            float Dz = bcz * d0 + mz * d1 + nz * d2 + Cz;

            size_t r = 3 + 3 * (size_t)t + j;
            out[(r * B + b) * 3 + 0] = Dx;
            out[(r * B + b) * 3 + 1] = Dy;
            out[(r * B + b) * 3 + 2] = Dz;

            Ax = Bx; Ay = By; Az = Bz;
            Bx = Cx; By = Cy; Bz = Cz;
            Cx = Dx; Cy = Dy; Cz = Dz;
        }
    }
}

// ---------------------------------------------------------------------------
extern "C" void kernel_launch(void* const* d_in, const int* in_sizes, int n_in,
                              void* d_out, int out_size, void* d_ws, size_t ws_size,
                              hipStream_t stream)
{
    const int*   seq      = (const int*)  d_in[0];
    const float* pssm     = (const float*)d_in[1];
    // d_in[2] = length (all full-length)
    const float* embed    = (const float*)d_in[3];
    const float* Wih_f    = (const float*)d_in[4];
    const float* Whh_f    = (const float*)d_in[5];
    const float* bih_f    = (const float*)d_in[6];
    const float* bhh_f    = (const float*)d_in[7];
    const float* Wih_b    = (const float*)d_in[8];
    const float* Whh_b    = (const float*)d_in[9];
    const float* bih_b    = (const float*)d_in[10];
    const float* bhh_b    = (const float*)d_in[11];
    const float* W_lin    = (const float*)d_in[12];
    const float* b_lin    = (const float*)d_in[13];
    const float* alphabet = (const float*)d_in[14];
    float* out = (float*)d_out;

    // workspace layout (~142 MB total)
    char* ws = (char*)d_ws;
    size_t off = 0;
    float* hr    = (float*)(ws + off); off += (size_t)4 * HB * 4;            // 512 KB
    int*   cnt   = (int*)  (ws + off); off += (size_t)2 * L * 4;             // 8 KB
    size_t zero_bytes = off;                                                 // one memset covers both
    float* E2    = (float*)(ws + off); off += (size_t)2 * 20 * 2048 * 4;     // 320 KB
    float* pt    = (float*)(ws + off); off += (size_t)L * PSSM * B * 4;      // 5.5 MB
    __hip_bfloat16* hs16_f = (__hip_bfloat16*)(ws + off); off += (size_t)L * HB * 2;  // 64 MB
    __hip_bfloat16* hs16_b = (__hip_bfloat16*)(ws + off); off += (size_t)L * HB * 2;  // 64 MB
    float* sp    = (float*)(ws + off); off += (size_t)L * B * 3 * 4;         // 768 KB
    float* cp    = (float*)(ws + off); off += (size_t)L * B * 3 * 4;         // 768 KB

    hipMemsetAsync(hr, 0, zero_bytes, stream);   // ring slots + counters

    prep_e2<<<dim3(320), dim3(256), 0, stream>>>(Wih_f, Wih_b, embed, E2);
    prep_pssm_t<<<dim3(L), dim3(64), 0, stream>>>(pssm, pt);

    lstm_persistent<<<dim3(2 * NWG_DIR), dim3(256), 0, stream>>>(
        E2, pt, seq, Wih_f, Whh_f, bih_f, bhh_f, Wih_b, Whh_b, bih_b, bhh_b,
        hr, hs16_f, hs16_b, cnt);

    proj_softmax<<<dim3(L), dim3(256), 0, stream>>>(hs16_f, hs16_b, W_lin, b_lin,
                                                    alphabet, sp, cp);
    geometry<<<dim3(1), dim3(64), 0, stream>>>(sp, cp, out);
}

// Round 4
// 37597.766 us; speedup vs baseline: 2.5128x; 1.0462x over previous
//
#include <hip/hip_runtime.h>
#include <hip/hip_bf16.h>
#include <math.h>

// Problem constants
constexpr int L    = 1024;
constexpr int B    = 64;
constexpr int H    = 512;
constexpr int ED   = 512;
constexpr int PSSM = 21;
constexpr int DIN  = ED + PSSM;    // 533
constexpr int LU   = 60;
constexpr int NWG_DIR = 128;       // workgroups per direction
constexpr int JPW  = H / NWG_DIR;  // hidden units per WG = 4
constexpr int HB   = H * B;        // 32768

// ---------------------------------------------------------------------------
// P0: E2[dir][s][col] = sum_{k<512} embed[s][k] * Wih_dir[col][k]
// ---------------------------------------------------------------------------
__global__ __launch_bounds__(256) void prep_e2(
    const float* __restrict__ Wih_f, const float* __restrict__ Wih_b,
    const float* __restrict__ embed, float* __restrict__ E2)
{
    int idx  = blockIdx.x * 256 + threadIdx.x;   // 0 .. 81919
    int col  = idx & 2047;
    int rest = idx >> 11;                        // dir*20 + s
    int s    = rest % 20;
    int dir  = rest / 20;
    const float* W  = dir ? Wih_b : Wih_f;
    const float* er = embed + (size_t)s * ED;    // wave-uniform row
    const float* wr = W + (size_t)col * DIN;
    float a = 0.f;
    #pragma unroll 8
    for (int k = 0; k < ED; ++k) a = fmaf(er[k], wr[k], a);
    E2[idx] = a;
}

// ---------------------------------------------------------------------------
// P1: pssm_t[t][kk][b] = pssm[t][b][kk]
// ---------------------------------------------------------------------------
__global__ void prep_pssm_t(const float* __restrict__ pssm, float* __restrict__ pt)
{
    int t = blockIdx.x, b = threadIdx.x;   // 64 threads
    for (int kk = 0; kk < PSSM; ++kk)
        pt[((size_t)t * PSSM + kk) * B + b] = pssm[((size_t)t * B + b) * PSSM + kk];
}

// ---------------------------------------------------------------------------
// K1: persistent bidirectional LSTM. 256 WGs (128 fwd + 128 bwd). ~136 KB of
// static LDS forces 1 WG/CU -> all 256 blocks co-resident on 256 CUs.
//
// R4 sync design: the h ring is exchanged ONLY through LLC-coherent bypass
// accesses (sc0 sc1): relaxed agent atomic stores on publish, raw
// global_load_dwordx4 sc0 sc1 on stage. No acquire fences anywhere in the
// loop -> no buffer_inv -> weights stay cached in L1/sL1/L2 across all 1024
// steps. Poll is a RELAXED atomic load by tid0 with s_sleep backoff.
// Publish is one RELEASE fetch_add per WG (wbl2 covers only ~0.5 KB of
// dirty hs16 lines).
// ---------------------------------------------------------------------------
__global__ __launch_bounds__(256) void lstm_persistent(
    const float* __restrict__ E2, const float* __restrict__ pt,
    const int* __restrict__ seq,
    const float* __restrict__ Wih_f, const float* __restrict__ Whh_f,
    const float* __restrict__ bih_f, const float* __restrict__ bhh_f,
    const float* __restrict__ Wih_b, const float* __restrict__ Whh_b,
    const float* __restrict__ bih_b, const float* __restrict__ bhh_b,
    float* __restrict__ hr,                    // [2 dir][2 slot][H][B]
    __hip_bfloat16* __restrict__ hs16_f,
    __hip_bfloat16* __restrict__ hs16_b,
    int* __restrict__ cnt)                     // [2][L]
{
    __shared__ float hsh[H][B];                // 128 KB staged h_{prev}
    __shared__ float zsh[4][JPW][B];           // 4 KB gate pre-activations
    __shared__ float csh[JPW][B];              // 1 KB cell state
    __shared__ float wpsh[4][JPW][PSSM];       // 1.3 KB pssm weight slice
    __shared__ float wesh[20][17];             // 1.4 KB E2 slice (padded)

    const int wg    = blockIdx.x;
    const int dir   = wg >> 7;                 // 0 fwd, 1 bwd
    const int wslot = wg & 127;
    const int j0    = wslot * JPW;
    const int tid   = threadIdx.x;
    const int b     = tid & 63;
    const int g     = __builtin_amdgcn_readfirstlane(tid >> 6); // gate 0..3

    const float* Wih = dir ? Wih_b : Wih_f;
    const float* Whh = dir ? Whh_b : Whh_f;
    const float* bih = dir ? bih_b : bih_f;
    const float* bhh = dir ? bhh_b : bhh_f;
    float*      ring = hr + (size_t)dir * 2 * HB;
    __hip_bfloat16* hs16 = dir ? hs16_b : hs16_f;
    int*       mycnt = cnt + dir * L;

    // fill pssm-weight slice + E2 slice + cell init
    for (int i = tid; i < 4 * JPW * PSSM; i += 256) {
        int gg = i / (JPW * PSSM), rem = i % (JPW * PSSM);
        int jj = rem / PSSM, kk = rem % PSSM;
        int col = gg * H + j0 + jj;
        wpsh[gg][jj][kk] = Wih[(size_t)col * DIN + ED + kk];
    }
    for (int i = tid; i < 20 * 16; i += 256) {
        int s = i >> 4, c = i & 15;
        int col = (c / JPW) * H + j0 + (c % JPW);
        wesh[s][c] = E2[(size_t)(dir * 20 + s) * 2048 + col];
    }
    csh[tid >> 6][tid & 63] = 0.f;

    // wave-uniform recurrent weight rows + bias
    const float* whhr[JPW];
    float bias[JPW];
    #pragma unroll
    for (int jj = 0; jj < JPW; ++jj) {
        int col = g * H + j0 + jj;
        whhr[jj] = Whh + (size_t)col * H;
        bias[jj] = bih[col] + bhh[col];
    }
    __syncthreads();

    int dead = 0;
    for (int s = 0; s < L; ++s) {
        const int t = dir ? (L - 1 - s) : s;

        // ---- input part (h-independent, overlaps other WGs' tails) ----
        float acc[JPW];
        int sb = seq[t * B + b];
        #pragma unroll
        for (int jj = 0; jj < JPW; ++jj)
            acc[jj] = bias[jj] + wesh[sb][g * JPW + jj];
        const float* ptr = pt + (size_t)t * PSSM * B + b;
        #pragma unroll
        for (int kk = 0; kk < PSSM; ++kk) {
            float pv = ptr[(size_t)kk * B];
            #pragma unroll
            for (int jj = 0; jj < JPW; ++jj)
                acc[jj] = fmaf(pv, wpsh[g][jj][kk], acc[jj]);
        }

        // ---- wait: tid0 RELAXED-polls the step-(s-1) counter (no cache ops) ----
        if (s > 0 && tid == 0 && !dead) {
            int it = 0;
            while (__hip_atomic_load(&mycnt[s - 1], __ATOMIC_RELAXED,
                                     __HIP_MEMORY_SCOPE_AGENT) < NWG_DIR) {
                __builtin_amdgcn_s_sleep(2);
                if (++it > (1 << 17)) { dead = 1; break; }   // anti-hang
            }
        }
        __syncthreads();

        // ---- stage h_{prev} ring slot (128 KB) into LDS via LLC-coherent
        //      bypass loads (sc0 sc1): no fence needed, caches untouched ----
        {
            const char* gbase = (const char*)(ring + (size_t)((s + 1) & 1) * HB)
                                + (size_t)tid * 16;
            char* lbase = (char*)&hsh[0][0] + (size_t)tid * 16;
            float4 tmp[16];
            #pragma unroll
            for (int bi = 0; bi < 2; ++bi) {
                #pragma unroll
                for (int it = 0; it < 16; ++it) {
                    asm volatile("global_load_dwordx4 %0, %1, off sc0 sc1"
                                 : "=v"(tmp[it])
                                 : "v"(gbase + (size_t)(bi * 16 + it) * 4096)
                                 : "memory");
                }
                asm volatile("s_waitcnt vmcnt(0)" ::: "memory");
                #pragma unroll
                for (int it = 0; it < 16; ++it)
                    *(float4*)(lbase + (size_t)(bi * 16 + it) * 4096) = tmp[it];
            }
        }
        __syncthreads();

        // ---- recurrent GEMM part: K = 512 ----
        #pragma unroll 8
        for (int k = 0; k < H; ++k) {
            float hv = hsh[k][b];
            #pragma unroll
            for (int jj = 0; jj < JPW; ++jj)
                acc[jj] = fmaf(hv, whhr[jj][k], acc[jj]);   // weight: scalar load
        }
        #pragma unroll
        for (int jj = 0; jj < JPW; ++jj) zsh[g][jj][b] = acc[jj];
        __syncthreads();

        // ---- gates: thread (jj, b) combines the 4 gate values ----
        {
            const int jj = tid >> 6;
            float iv = zsh[0][jj][b], fv = zsh[1][jj][b];
            float gv = zsh[2][jj][b], ov = zsh[3][jj][b];
            iv = 1.f / (1.f + __expf(-iv));
            fv = 1.f / (1.f + __expf(-fv));
            gv = tanhf(gv);
            ov = 1.f / (1.f + __expf(-ov));
            float c = fv * csh[jj][b] + iv * gv;
            csh[jj][b] = c;
            float hv = ov * tanhf(c);
            // publish h via LLC-coherent relaxed atomic store (bypass)
            __hip_atomic_store(&ring[(size_t)(s & 1) * HB + (size_t)(j0 + jj) * B + b],
                               hv, __ATOMIC_RELAXED, __HIP_MEMORY_SCOPE_AGENT);
            hs16[(size_t)t * HB + (size_t)(j0 + jj) * B + b] = __float2bfloat16(hv);
        }
        __syncthreads();   // compiler drains vmcnt before the barrier
        if (tid == 0)      // RELEASE: orders the bypass h-stores before the bump
            __hip_atomic_fetch_add(&mycnt[s], 1, __ATOMIC_RELEASE,
                                   __HIP_MEMORY_SCOPE_AGENT);
    }
}

// ---------------------------------------------------------------------------
// K2: logits -> softmax -> alphabet mix -> normalized sin/cos of torsions.
// ---------------------------------------------------------------------------
__global__ __launch_bounds__(256) void proj_softmax(
    const __hip_bfloat16* __restrict__ hs16_f, const __hip_bfloat16* __restrict__ hs16_b,
    const float* __restrict__ W_lin, const float* __restrict__ b_lin,
    const float* __restrict__ alphabet, float* __restrict__ sp, float* __restrict__ cp)
{
    const int t   = blockIdx.x;
    const int tid = threadIdx.x;
    const int b   = tid & 63;
    const int ug  = __builtin_amdgcn_readfirstlane(tid >> 6);  // 0..3
    constexpr int NU = 15;                                     // 60 = 4*15

    __shared__ float lg[B][LU];
    __shared__ float sa[LU][3], ca[LU][3];
    if (tid < LU) {
        for (int k = 0; k < 3; ++k) {
            float a = alphabet[tid * 3 + k];
            sa[tid][k] = __sinf(a);
            ca[tid][k] = __cosf(a);
        }
    }

    const int u0 = ug * NU;
    float acc[NU];
    #pragma unroll
    for (int i = 0; i < NU; ++i) acc[i] = b_lin[u0 + i];

    const __hip_bfloat16* hf = hs16_f + (size_t)t * HB + b;
    const __hip_bfloat16* hb = hs16_b + (size_t)t * HB + b;
    #pragma unroll 4
    for (int j = 0; j < H; ++j) {
        float hv = __bfloat162float(hf[(size_t)j * B]);
        #pragma unroll
        for (int i = 0; i < NU; ++i)
            acc[i] = fmaf(hv, W_lin[(size_t)(u0 + i) * (2 * H) + j], acc[i]);
    }
    #pragma unroll 4
    for (int j = 0; j < H; ++j) {
        float hv = __bfloat162float(hb[(size_t)j * B]);
        #pragma unroll
        for (int i = 0; i < NU; ++i)
            acc[i] = fmaf(hv, W_lin[(size_t)(u0 + i) * (2 * H) + H + j], acc[i]);
    }
    #pragma unroll
    for (int i = 0; i < NU; ++i) lg[b][u0 + i] = acc[i];
    __syncthreads();

    if (tid < B) {
        float m = -1e30f;
        for (int u = 0; u < LU; ++u) m = fmaxf(m, lg[tid][u]);
        float sv[3] = {0, 0, 0}, cv[3] = {0, 0, 0};
        for (int u = 0; u < LU; ++u) {
            float e = __expf(lg[tid][u] - m);
            for (int k = 0; k < 3; ++k) {
                sv[k] = fmaf(e, sa[u][k], sv[k]);
                cv[k] = fmaf(e, ca[u][k], cv[k]);
            }
        }
        for (int k = 0; k < 3; ++k) {
            float r = rsqrtf(sv[k] * sv[k] + cv[k] * cv[k]);
            sp[((size_t)t * B + tid) * 3 + k] = sv[k] * r;
            cp[((size_t)t * B + tid) * 3 + k] = cv[k] * r;
        }
    }
}

// ---------------------------------------------------------------------------
// K3: sequential NeRF extension. One wave, lane = chain.
// ---------------------------------------------------------------------------
__global__ void geometry(const float* __restrict__ sp, const float* __restrict__ cp,
                         float* __restrict__ out)
{
    const int b = threadIdx.x;   // 64
    const float Rj[3] = {132.868f, 145.801f, 152.326f};
    const float Tj[3] = {2.028f, 2.124f, 1.941f};
    float cT[3], sT[3];
    for (int j = 0; j < 3; ++j) { cT[j] = cosf(Tj[j]); sT[j] = sinf(Tj[j]); }

    for (int r = 0; r < 3; ++r)
        for (int c = 0; c < 3; ++c)
            out[((size_t)r * B + b) * 3 + c] = (r == c) ? 1.f : 0.f;

    float Ax = 1.f, Ay = 0.f, Az = 0.f;
    float Bx = 0.f, By = 1.f, Bz = 0.f;
    float Cx = 0.f, Cy = 0.f, Cz = 1.f;

    for (int t = 0; t < L; ++t) {
        for (int j = 0; j < 3; ++j) {
            float sP = sp[((size_t)t * B + b) * 3 + j];
            float cP = cp[((size_t)t * B + b) * 3 + j];
            float d0 = -Rj[j] * cT[j];
            float d1 =  Rj[j] * cP * sT[j];
            float d2 =  Rj[j] * sP * sT[j];

            float bcx = Cx - Bx, bcy = Cy - By, bcz = Cz - Bz;
            float inv = rsqrtf(bcx * bcx + bcy * bcy + bcz * bcz);
            bcx *= inv; bcy *= inv; bcz *= inv;

            float abx = Bx - Ax, aby = By - Ay, abz = Bz - Az;
            float nx = aby * bcz - abz * bcy;
            float ny = abz * bcx - abx * bcz;
            float nz = abx * bcy - aby * bcx;
            inv = rsqrtf(nx * nx + ny * ny + nz * nz);
            nx *= inv; ny *= inv; nz *= inv;

            float mx = ny * bcz - nz * bcy;
            float my = nz * bcx - nx * bcz;
            float mz = nx * bcy - ny * bcx;

            float Dx = bcx * d0 + mx * d1 + nx * d2 + Cx;
            float Dy = bcy * d0 + my * d1 + ny * d2 + Cy;
            float Dz = bcz * d0 + mz * d1 + nz * d2 + Cz;

            size_t r = 3 + 3 * (size_t)t + j;
            out[(r * B + b) * 3 + 0] = Dx;
            out[(r * B + b) * 3 + 1] = Dy;
            out[(r * B + b) * 3 + 2] = Dz;

            Ax = Bx; Ay = By; Az = Bz;
            Bx = Cx; By = Cy; Bz = Cz;
            Cx = Dx; Cy = Dy; Cz = Dz;
        }
    }
}

// ---------------------------------------------------------------------------
extern "C" void kernel_launch(void* const* d_in, const int* in_sizes, int n_in,
                              void* d_out, int out_size, void* d_ws, size_t ws_size,
                              hipStream_t stream)
{
    const int*   seq      = (const int*)  d_in[0];
    const float* pssm     = (const float*)d_in[1];
    // d_in[2] = length (all full-length)
    const float* embed    = (const float*)d_in[3];
    const float* Wih_f    = (const float*)d_in[4];
    const float* Whh_f    = (const float*)d_in[5];
    const float* bih_f    = (const float*)d_in[6];
    const float* bhh_f    = (const float*)d_in[7];
    const float* Wih_b    = (const float*)d_in[8];
    const float* Whh_b    = (const float*)d_in[9];
    const float* bih_b    = (const float*)d_in[10];
    const float* bhh_b    = (const float*)d_in[11];
    const float* W_lin    = (const float*)d_in[12];
    const float* b_lin    = (const float*)d_in[13];
    const float* alphabet = (const float*)d_in[14];
    float* out = (float*)d_out;

    // workspace layout (~142 MB total)
    char* ws = (char*)d_ws;
    size_t off = 0;
    float* hr    = (float*)(ws + off); off += (size_t)4 * HB * 4;            // 512 KB
    int*   cnt   = (int*)  (ws + off); off += (size_t)2 * L * 4;             // 8 KB
    size_t zero_bytes = off;                                                 // one memset covers both
    float* E2    = (float*)(ws + off); off += (size_t)2 * 20 * 2048 * 4;     // 320 KB
    float* pt    = (float*)(ws + off); off += (size_t)L * PSSM * B * 4;      // 5.5 MB
    __hip_bfloat16* hs16_f = (__hip_bfloat16*)(ws + off); off += (size_t)L * HB * 2;  // 64 MB
    __hip_bfloat16* hs16_b = (__hip_bfloat16*)(ws + off); off += (size_t)L * HB * 2;  // 64 MB
    float* sp    = (float*)(ws + off); off += (size_t)L * B * 3 * 4;         // 768 KB
    float* cp    = (float*)(ws + off); off += (size_t)L * B * 3 * 4;         // 768 KB

    hipMemsetAsync(hr, 0, zero_bytes, stream);   // ring slots + counters

    prep_e2<<<dim3(320), dim3(256), 0, stream>>>(Wih_f, Wih_b, embed, E2);
    prep_pssm_t<<<dim3(L), dim3(64), 0, stream>>>(pssm, pt);

    lstm_persistent<<<dim3(2 * NWG_DIR), dim3(256), 0, stream>>>(
        E2, pt, seq, Wih_f, Whh_f, bih_f, bhh_f, Wih_b, Whh_b, bih_b, bhh_b,
        hr, hs16_f, hs16_b, cnt);

    proj_softmax<<<dim3(L), dim3(256), 0, stream>>>(hs16_f, hs16_b, W_lin, b_lin,
                                                    alphabet, sp, cp);
    geometry<<<dim3(1), dim3(64), 0, stream>>>(sp, cp, out);
}

// Round 5
// 26731.384 us; speedup vs baseline: 3.5342x; 1.4065x over previous
//
#include <hip/hip_runtime.h>
#include <hip/hip_bf16.h>
#include <math.h>

// Problem constants
constexpr int L    = 1024;
constexpr int B    = 64;
constexpr int H    = 512;
constexpr int ED   = 512;
constexpr int PSSM = 21;
constexpr int DIN  = ED + PSSM;    // 533
constexpr int LU   = 60;
constexpr int NWG_DIR = 128;       // workgroups per direction
constexpr int JPW  = H / NWG_DIR;  // hidden units per WG = 4
constexpr int HB   = H * B;        // 32768

// ---------------------------------------------------------------------------
// P0: E2[dir][s][col] = sum_{k<512} embed[s][k] * Wih_dir[col][k]
// ---------------------------------------------------------------------------
__global__ __launch_bounds__(256) void prep_e2(
    const float* __restrict__ Wih_f, const float* __restrict__ Wih_b,
    const float* __restrict__ embed, float* __restrict__ E2)
{
    int idx  = blockIdx.x * 256 + threadIdx.x;   // 0 .. 81919
    int col  = idx & 2047;
    int rest = idx >> 11;                        // dir*20 + s
    int s    = rest % 20;
    int dir  = rest / 20;
    const float* W  = dir ? Wih_b : Wih_f;
    const float* er = embed + (size_t)s * ED;    // wave-uniform row
    const float* wr = W + (size_t)col * DIN;
    float a = 0.f;
    #pragma unroll 8
    for (int k = 0; k < ED; ++k) a = fmaf(er[k], wr[k], a);
    E2[idx] = a;
}

// ---------------------------------------------------------------------------
// P1: pssm_t[t][kk][b] = pssm[t][b][kk]
// ---------------------------------------------------------------------------
__global__ void prep_pssm_t(const float* __restrict__ pssm, float* __restrict__ pt)
{
    int t = blockIdx.x, b = threadIdx.x;   // 64 threads
    for (int kk = 0; kk < PSSM; ++kk)
        pt[((size_t)t * PSSM + kk) * B + b] = pssm[((size_t)t * B + b) * PSSM + kk];
}

// ---------------------------------------------------------------------------
// K1: persistent bidirectional LSTM. 256 WGs (128 fwd + 128 bwd). ~136 KB of
// static LDS forces 1 WG/CU -> all 256 blocks co-resident on 256 CUs.
//
// R5 sync design: ZERO cache-maintenance ops in the loop. All cross-WG data
// (h ring + flags) moves through LLC-coherent bypass accesses (sc0 sc1).
// Publish: per-WG relaxed bypass store of s+1 into its OWN flag word
// (no same-line RMW serialization, no buffer_wbl2). Ordering: __syncthreads
// drains vmcnt (h stores LLC-visible) before tid0's flag store issues.
// Wait: wave 0 polls all 128 flags (2 bypass loads/lane + __all), s_sleep
// backoff; waves 1-3 sit at the barrier. Weights stay cached in L1/L2 for
// all 1024 steps (read-only, never invalidated).
// ---------------------------------------------------------------------------
__global__ __launch_bounds__(256) void lstm_persistent(
    const float* __restrict__ E2, const float* __restrict__ pt,
    const int* __restrict__ seq,
    const float* __restrict__ Wih_f, const float* __restrict__ Whh_f,
    const float* __restrict__ bih_f, const float* __restrict__ bhh_f,
    const float* __restrict__ Wih_b, const float* __restrict__ Whh_b,
    const float* __restrict__ bih_b, const float* __restrict__ bhh_b,
    float* __restrict__ hr,                    // [2 dir][2 slot][H][B]
    __hip_bfloat16* __restrict__ hs16_f,
    __hip_bfloat16* __restrict__ hs16_b,
    int* __restrict__ flags)                   // [2][128]
{
    __shared__ float hsh[H][B];                // 128 KB staged h_{prev}
    __shared__ float zsh[4][JPW][B];           // 4 KB gate pre-activations
    __shared__ float csh[JPW][B];              // 1 KB cell state
    __shared__ float wpsh[4][JPW][PSSM];       // 1.3 KB pssm weight slice
    __shared__ float wesh[20][17];             // 1.4 KB E2 slice (padded)

    const int wg    = blockIdx.x;
    const int dir   = wg >> 7;                 // 0 fwd, 1 bwd
    const int wslot = wg & 127;
    const int j0    = wslot * JPW;
    const int tid   = threadIdx.x;
    const int b     = tid & 63;
    const int g     = __builtin_amdgcn_readfirstlane(tid >> 6); // gate 0..3

    const float* Wih = dir ? Wih_b : Wih_f;
    const float* Whh = dir ? Whh_b : Whh_f;
    const float* bih = dir ? bih_b : bih_f;
    const float* bhh = dir ? bhh_b : bhh_f;
    float*      ring = hr + (size_t)dir * 2 * HB;
    __hip_bfloat16* hs16 = dir ? hs16_b : hs16_f;
    int*         flg = flags + dir * 128;

    // fill pssm-weight slice + E2 slice + cell init
    for (int i = tid; i < 4 * JPW * PSSM; i += 256) {
        int gg = i / (JPW * PSSM), rem = i % (JPW * PSSM);
        int jj = rem / PSSM, kk = rem % PSSM;
        int col = gg * H + j0 + jj;
        wpsh[gg][jj][kk] = Wih[(size_t)col * DIN + ED + kk];
    }
    for (int i = tid; i < 20 * 16; i += 256) {
        int s = i >> 4, c = i & 15;
        int col = (c / JPW) * H + j0 + (c % JPW);
        wesh[s][c] = E2[(size_t)(dir * 20 + s) * 2048 + col];
    }
    csh[tid >> 6][tid & 63] = 0.f;

    // wave-uniform recurrent weight rows + bias
    const float* whhr[JPW];
    float bias[JPW];
    #pragma unroll
    for (int jj = 0; jj < JPW; ++jj) {
        int col = g * H + j0 + jj;
        whhr[jj] = Whh + (size_t)col * H;
        bias[jj] = bih[col] + bhh[col];
    }
    __syncthreads();

    int dead = 0;
    for (int s = 0; s < L; ++s) {
        const int t = dir ? (L - 1 - s) : s;

        // ---- input part (h-independent, overlaps other WGs' tails) ----
        float acc[JPW];
        int sb = seq[t * B + b];
        #pragma unroll
        for (int jj = 0; jj < JPW; ++jj)
            acc[jj] = bias[jj] + wesh[sb][g * JPW + jj];
        const float* ptr = pt + (size_t)t * PSSM * B + b;
        #pragma unroll
        for (int kk = 0; kk < PSSM; ++kk) {
            float pv = ptr[(size_t)kk * B];
            #pragma unroll
            for (int jj = 0; jj < JPW; ++jj)
                acc[jj] = fmaf(pv, wpsh[g][jj][kk], acc[jj]);
        }

        // ---- wait: wave 0 polls all 128 flags via LLC bypass loads ----
        if (s > 0 && tid < 64 && !dead) {
            const int* f1 = flg + tid;
            const int* f2 = flg + 64 + tid;
            int it = 0;
            while (true) {
                int a, c2;
                asm volatile("global_load_dword %0, %2, off sc0 sc1\n\t"
                             "global_load_dword %1, %3, off sc0 sc1\n\t"
                             "s_waitcnt vmcnt(0)"
                             : "=&v"(a), "=&v"(c2)
                             : "v"(f1), "v"(f2)
                             : "memory");
                if (__all(a >= s && c2 >= s)) break;
                __builtin_amdgcn_s_sleep(2);
                if (++it > (1 << 17)) { dead = 1; break; }   // anti-hang
            }
        }
        __syncthreads();

        // ---- stage h_{prev} ring slot (128 KB) into LDS via LLC bypass ----
        {
            const char* gbase = (const char*)(ring + (size_t)((s + 1) & 1) * HB)
                                + (size_t)tid * 16;
            char* lbase = (char*)&hsh[0][0] + (size_t)tid * 16;
            float4 tmp[16];
            #pragma unroll
            for (int bi = 0; bi < 2; ++bi) {
                #pragma unroll
                for (int it = 0; it < 16; ++it) {
                    asm volatile("global_load_dwordx4 %0, %1, off sc0 sc1"
                                 : "=v"(tmp[it])
                                 : "v"(gbase + (size_t)(bi * 16 + it) * 4096)
                                 : "memory");
                }
                asm volatile("s_waitcnt vmcnt(0)" ::: "memory");
                #pragma unroll
                for (int it = 0; it < 16; ++it)
                    *(float4*)(lbase + (size_t)(bi * 16 + it) * 4096) = tmp[it];
            }
        }
        __syncthreads();

        // ---- recurrent GEMM part: K = 512 ----
        #pragma unroll 8
        for (int k = 0; k < H; ++k) {
            float hv = hsh[k][b];
            #pragma unroll
            for (int jj = 0; jj < JPW; ++jj)
                acc[jj] = fmaf(hv, whhr[jj][k], acc[jj]);   // weight: scalar load
        }
        #pragma unroll
        for (int jj = 0; jj < JPW; ++jj) zsh[g][jj][b] = acc[jj];
        __syncthreads();

        // ---- gates: thread (jj, b) combines the 4 gate values ----
        {
            const int jj = tid >> 6;
            float iv = zsh[0][jj][b], fv = zsh[1][jj][b];
            float gv = zsh[2][jj][b], ov = zsh[3][jj][b];
            iv = 1.f / (1.f + __expf(-iv));
            fv = 1.f / (1.f + __expf(-fv));
            gv = tanhf(gv);
            ov = 1.f / (1.f + __expf(-ov));
            float c = fv * csh[jj][b] + iv * gv;
            csh[jj][b] = c;
            float hv = ov * tanhf(c);
            // publish h via LLC bypass store (coherent at LLC, no cache ops)
            float* hdst = &ring[(size_t)(s & 1) * HB + (size_t)(j0 + jj) * B + b];
            asm volatile("global_store_dword %0, %1, off sc0 sc1"
                         :: "v"(hdst), "v"(hv) : "memory");
            hs16[(size_t)t * HB + (size_t)(j0 + jj) * B + b] = __float2bfloat16(hv);
        }
        __syncthreads();   // drains vmcnt: all h stores LLC-visible past here
        if (tid == 0) {    // flag publish: relaxed bypass store, own word
            int val = s + 1;
            asm volatile("global_store_dword %0, %1, off sc0 sc1"
                         :: "v"(flg + wslot), "v"(val) : "memory");
        }
    }
}

// ---------------------------------------------------------------------------
// K2: logits -> softmax -> alphabet mix -> normalized sin/cos of torsions.
// ---------------------------------------------------------------------------
__global__ __launch_bounds__(256) void proj_softmax(
    const __hip_bfloat16* __restrict__ hs16_f, const __hip_bfloat16* __restrict__ hs16_b,
    const float* __restrict__ W_lin, const float* __restrict__ b_lin,
    const float* __restrict__ alphabet, float* __restrict__ sp, float* __restrict__ cp)
{
    const int t   = blockIdx.x;
    const int tid = threadIdx.x;
    const int b   = tid & 63;
    const int ug  = __builtin_amdgcn_readfirstlane(tid >> 6);  // 0..3
    constexpr int NU = 15;                                     // 60 = 4*15

    __shared__ float lg[B][LU];
    __shared__ float sa[LU][3], ca[LU][3];
    if (tid < LU) {
        for (int k = 0; k < 3; ++k) {
            float a = alphabet[tid * 3 + k];
            sa[tid][k] = __sinf(a);
            ca[tid][k] = __cosf(a);
        }
    }

    const int u0 = ug * NU;
    float acc[NU];
    #pragma unroll
    for (int i = 0; i < NU; ++i) acc[i] = b_lin[u0 + i];

    const __hip_bfloat16* hf = hs16_f + (size_t)t * HB + b;
    const __hip_bfloat16* hb = hs16_b + (size_t)t * HB + b;
    #pragma unroll 4
    for (int j = 0; j < H; ++j) {
        float hv = __bfloat162float(hf[(size_t)j * B]);
        #pragma unroll
        for (int i = 0; i < NU; ++i)
            acc[i] = fmaf(hv, W_lin[(size_t)(u0 + i) * (2 * H) + j], acc[i]);
    }
    #pragma unroll 4
    for (int j = 0; j < H; ++j) {
        float hv = __bfloat162float(hb[(size_t)j * B]);
        #pragma unroll
        for (int i = 0; i < NU; ++i)
            acc[i] = fmaf(hv, W_lin[(size_t)(u0 + i) * (2 * H) + H + j], acc[i]);
    }
    #pragma unroll
    for (int i = 0; i < NU; ++i) lg[b][u0 + i] = acc[i];
    __syncthreads();

    if (tid < B) {
        float m = -1e30f;
        for (int u = 0; u < LU; ++u) m = fmaxf(m, lg[tid][u]);
        float sv[3] = {0, 0, 0}, cv[3] = {0, 0, 0};
        for (int u = 0; u < LU; ++u) {
            float e = __expf(lg[tid][u] - m);
            for (int k = 0; k < 3; ++k) {
                sv[k] = fmaf(e, sa[u][k], sv[k]);
                cv[k] = fmaf(e, ca[u][k], cv[k]);
            }
        }
        for (int k = 0; k < 3; ++k) {
            float r = rsqrtf(sv[k] * sv[k] + cv[k] * cv[k]);
            sp[((size_t)t * B + tid) * 3 + k] = sv[k] * r;
            cp[((size_t)t * B + tid) * 3 + k] = cv[k] * r;
        }
    }
}

// ---------------------------------------------------------------------------
// K3: sequential NeRF extension. One wave, lane = chain.
// ---------------------------------------------------------------------------
__global__ void geometry(const float* __restrict__ sp, const float* __restrict__ cp,
                         float* __restrict__ out)
{
    const int b = threadIdx.x;   // 64
    const float Rj[3] = {132.868f, 145.801f, 152.326f};
    const float Tj[3] = {2.028f, 2.124f, 1.941f};
    float cT[3], sT[3];
    for (int j = 0; j < 3; ++j) { cT[j] = cosf(Tj[j]); sT[j] = sinf(Tj[j]); }

    for (int r = 0; r < 3; ++r)
        for (int c = 0; c < 3; ++c)
            out[((size_t)r * B + b) * 3 + c] = (r == c) ? 1.f : 0.f;

    float Ax = 1.f, Ay = 0.f, Az = 0.f;
    float Bx = 0.f, By = 1.f, Bz = 0.f;
    float Cx = 0.f, Cy = 0.f, Cz = 1.f;

    for (int t = 0; t < L; ++t) {
        for (int j = 0; j < 3; ++j) {
            float sP = sp[((size_t)t * B + b) * 3 + j];
            float cP = cp[((size_t)t * B + b) * 3 + j];
            float d0 = -Rj[j] * cT[j];
            float d1 =  Rj[j] * cP * sT[j];
            float d2 =  Rj[j] * sP * sT[j];

            float bcx = Cx - Bx, bcy = Cy - By, bcz = Cz - Bz;
            float inv = rsqrtf(bcx * bcx + bcy * bcy + bcz * bcz);
            bcx *= inv; bcy *= inv; bcz *= inv;

            float abx = Bx - Ax, aby = By - Ay, abz = Bz - Az;
            float nx = aby * bcz - abz * bcy;
            float ny = abz * bcx - abx * bcz;
            float nz = abx * bcy - aby * bcx;
            inv = rsqrtf(nx * nx + ny * ny + nz * nz);
            nx *= inv; ny *= inv; nz *= inv;

            float mx = ny * bcz - nz * bcy;
            float my = nz * bcx - nx * bcz;
            float mz = nx * bcy - ny * bcx;

            float Dx = bcx * d0 + mx * d1 + nx * d2 + Cx;
            float Dy = bcy * d0 + my * d1 + ny * d2 + Cy;
            float Dz = bcz * d0 + mz * d1 + nz * d2 + Cz;

            size_t r = 3 + 3 * (size_t)t + j;
            out[(r * B + b) * 3 + 0] = Dx;
            out[(r * B + b) * 3 + 1] = Dy;
            out[(r * B + b) * 3 + 2] = Dz;

            Ax = Bx; Ay = By; Az = Bz;
            Bx = Cx; By = Cy; Bz = Cz;
            Cx = Dx; Cy = Dy; Cz = Dz;
        }
    }
}

// ---------------------------------------------------------------------------
extern "C" void kernel_launch(void* const* d_in, const int* in_sizes, int n_in,
                              void* d_out, int out_size, void* d_ws, size_t ws_size,
                              hipStream_t stream)
{
    const int*   seq      = (const int*)  d_in[0];
    const float* pssm     = (const float*)d_in[1];
    // d_in[2] = length (all full-length)
    const float* embed    = (const float*)d_in[3];
    const float* Wih_f    = (const float*)d_in[4];
    const float* Whh_f    = (const float*)d_in[5];
    const float* bih_f    = (const float*)d_in[6];
    const float* bhh_f    = (const float*)d_in[7];
    const float* Wih_b    = (const float*)d_in[8];
    const float* Whh_b    = (const float*)d_in[9];
    const float* bih_b    = (const float*)d_in[10];
    const float* bhh_b    = (const float*)d_in[11];
    const float* W_lin    = (const float*)d_in[12];
    const float* b_lin    = (const float*)d_in[13];
    const float* alphabet = (const float*)d_in[14];
    float* out = (float*)d_out;

    // workspace layout (~142 MB total)
    char* ws = (char*)d_ws;
    size_t off = 0;
    float* hr    = (float*)(ws + off); off += (size_t)4 * HB * 4;            // 512 KB
    int*   flags = (int*)  (ws + off); off += 256 * 4;                       // 1 KB
    size_t zero_bytes = off;                                                 // one memset covers both
    float* E2    = (float*)(ws + off); off += (size_t)2 * 20 * 2048 * 4;     // 320 KB
    float* pt    = (float*)(ws + off); off += (size_t)L * PSSM * B * 4;      // 5.5 MB
    __hip_bfloat16* hs16_f = (__hip_bfloat16*)(ws + off); off += (size_t)L * HB * 2;  // 64 MB
    __hip_bfloat16* hs16_b = (__hip_bfloat16*)(ws + off); off += (size_t)L * HB * 2;  // 64 MB
    float* sp    = (float*)(ws + off); off += (size_t)L * B * 3 * 4;         // 768 KB
    float* cp    = (float*)(ws + off); off += (size_t)L * B * 3 * 4;         // 768 KB

    hipMemsetAsync(hr, 0, zero_bytes, stream);   // ring slots + flags

    prep_e2<<<dim3(320), dim3(256), 0, stream>>>(Wih_f, Wih_b, embed, E2);
    prep_pssm_t<<<dim3(L), dim3(64), 0, stream>>>(pssm, pt);

    lstm_persistent<<<dim3(2 * NWG_DIR), dim3(256), 0, stream>>>(
        E2, pt, seq, Wih_f, Whh_f, bih_f, bhh_f, Wih_b, Whh_b, bih_b, bhh_b,
        hr, hs16_f, hs16_b, flags);

    proj_softmax<<<dim3(L), dim3(256), 0, stream>>>(hs16_f, hs16_b, W_lin, b_lin,
                                                    alphabet, sp, cp);
    geometry<<<dim3(1), dim3(64), 0, stream>>>(sp, cp, out);
}

// Round 6
// 25089.171 us; speedup vs baseline: 3.7656x; 1.0655x over previous
//
#include <hip/hip_runtime.h>
#include <hip/hip_bf16.h>
#include <math.h>

// Problem constants
constexpr int L    = 1024;
constexpr int B    = 64;
constexpr int H    = 512;
constexpr int ED   = 512;
constexpr int PSSM = 21;
constexpr int DIN  = ED + PSSM;    // 533
constexpr int LU   = 60;
constexpr int NWG_DIR = 128;       // workgroups per direction
constexpr int JPW  = H / NWG_DIR;  // hidden units per WG = 4
constexpr int HB   = H * B;        // 32768

// ---------------------------------------------------------------------------
// P0: E2[dir][s][col] = sum_{k<512} embed[s][k] * Wih_dir[col][k]
// ---------------------------------------------------------------------------
__global__ __launch_bounds__(256) void prep_e2(
    const float* __restrict__ Wih_f, const float* __restrict__ Wih_b,
    const float* __restrict__ embed, float* __restrict__ E2)
{
    int idx  = blockIdx.x * 256 + threadIdx.x;   // 0 .. 81919
    int col  = idx & 2047;
    int rest = idx >> 11;                        // dir*20 + s
    int s    = rest % 20;
    int dir  = rest / 20;
    const float* W  = dir ? Wih_b : Wih_f;
    const float* er = embed + (size_t)s * ED;    // wave-uniform row
    const float* wr = W + (size_t)col * DIN;
    float a = 0.f;
    #pragma unroll 8
    for (int k = 0; k < ED; ++k) a = fmaf(er[k], wr[k], a);
    E2[idx] = a;
}

// ---------------------------------------------------------------------------
// P1: pssm_t[t][kk][b] = pssm[t][b][kk]
// ---------------------------------------------------------------------------
__global__ void prep_pssm_t(const float* __restrict__ pssm, float* __restrict__ pt)
{
    int t = blockIdx.x, b = threadIdx.x;   // 64 threads
    for (int kk = 0; kk < PSSM; ++kk)
        pt[((size_t)t * PSSM + kk) * B + b] = pssm[((size_t)t * B + b) * PSSM + kk];
}

// ---------------------------------------------------------------------------
// K1: persistent bidirectional LSTM. 256 WGs (128 fwd + 128 bwd). ~136 KB of
// static LDS forces 1 WG/CU -> all 256 blocks co-resident on 256 CUs.
//
// R6 sync design: hierarchical flags to kill LLC poll congestion.
//  - publish: per-WG bypass store of s+1 into its own flag word (as R5).
//  - aggregate: WG 0 of each direction polls all 128 flags (64 lanes x 2
//    bypass loads), then bypass-stores ONE super-flag (own cacheline).
//  - wait: all other WGs poll the super-flag with a single lane (tid0).
//  Device-wide poll traffic: ~255 lane-loads/round on 2 lines, vs 32K on 4
//  in R5 (the LLC slices serving the flag lines were saturated, queueing
//  the h publishes and staging loads behind poll storms).
// All cross-WG data still moves via LLC-coherent bypass (sc0 sc1); zero
// cache-maintenance ops in the loop; weights stay cached all 1024 steps.
// ---------------------------------------------------------------------------
__global__ __launch_bounds__(256) void lstm_persistent(
    const float* __restrict__ E2, const float* __restrict__ pt,
    const int* __restrict__ seq,
    const float* __restrict__ Wih_f, const float* __restrict__ Whh_f,
    const float* __restrict__ bih_f, const float* __restrict__ bhh_f,
    const float* __restrict__ Wih_b, const float* __restrict__ Whh_b,
    const float* __restrict__ bih_b, const float* __restrict__ bhh_b,
    float* __restrict__ hr,                    // [2 dir][2 slot][H][B]
    __hip_bfloat16* __restrict__ hs16_f,
    __hip_bfloat16* __restrict__ hs16_b,
    int* __restrict__ flags)                   // [2][128] + supers @ +512
{
    __shared__ float hsh[H][B];                // 128 KB staged h_{prev}
    __shared__ float zsh[4][JPW][B];           // 4 KB gate pre-activations
    __shared__ float csh[JPW][B];              // 1 KB cell state
    __shared__ float wpsh[4][JPW][PSSM];       // 1.3 KB pssm weight slice
    __shared__ float wesh[20][17];             // 1.4 KB E2 slice (padded)

    const int wg    = blockIdx.x;
    const int dir   = wg >> 7;                 // 0 fwd, 1 bwd
    const int wslot = wg & 127;
    const int j0    = wslot * JPW;
    const int tid   = threadIdx.x;
    const int b     = tid & 63;
    const int g     = __builtin_amdgcn_readfirstlane(tid >> 6); // gate 0..3

    const float* Wih = dir ? Wih_b : Wih_f;
    const float* Whh = dir ? Whh_b : Whh_f;
    const float* bih = dir ? bih_b : bih_f;
    const float* bhh = dir ? bhh_b : bhh_f;
    float*      ring = hr + (size_t)dir * 2 * HB;
    __hip_bfloat16* hs16 = dir ? hs16_b : hs16_f;
    int*         flg = flags + dir * 128;
    int*         sup = flags + 512 + dir * 32;   // own 128-B line per dir

    // fill pssm-weight slice + E2 slice + cell init
    for (int i = tid; i < 4 * JPW * PSSM; i += 256) {
        int gg = i / (JPW * PSSM), rem = i % (JPW * PSSM);
        int jj = rem / PSSM, kk = rem % PSSM;
        int col = gg * H + j0 + jj;
        wpsh[gg][jj][kk] = Wih[(size_t)col * DIN + ED + kk];
    }
    for (int i = tid; i < 20 * 16; i += 256) {
        int s = i >> 4, c = i & 15;
        int col = (c / JPW) * H + j0 + (c % JPW);
        wesh[s][c] = E2[(size_t)(dir * 20 + s) * 2048 + col];
    }
    csh[tid >> 6][tid & 63] = 0.f;

    // wave-uniform recurrent weight rows + bias
    const float* whhr[JPW];
    float bias[JPW];
    #pragma unroll
    for (int jj = 0; jj < JPW; ++jj) {
        int col = g * H + j0 + jj;
        whhr[jj] = Whh + (size_t)col * H;
        bias[jj] = bih[col] + bhh[col];
    }
    __syncthreads();

    int dead = 0;
    for (int s = 0; s < L; ++s) {
        const int t = dir ? (L - 1 - s) : s;

        // ---- input part (h-independent, overlaps other WGs' tails) ----
        float acc[JPW];
        int sb = seq[t * B + b];
        #pragma unroll
        for (int jj = 0; jj < JPW; ++jj)
            acc[jj] = bias[jj] + wesh[sb][g * JPW + jj];
        const float* ptr = pt + (size_t)t * PSSM * B + b;
        #pragma unroll
        for (int kk = 0; kk < PSSM; ++kk) {
            float pv = ptr[(size_t)kk * B];
            #pragma unroll
            for (int jj = 0; jj < JPW; ++jj)
                acc[jj] = fmaf(pv, wpsh[g][jj][kk], acc[jj]);
        }

        // ---- hierarchical wait ----
        if (s > 0 && !dead) {
            if (wslot == 0) {
                // aggregator: wave 0 polls all 128 flags, then sets super=s
                if (tid < 64) {
                    const int* f1 = flg + tid;
                    const int* f2 = flg + 64 + tid;
                    int it = 0;
                    while (true) {
                        int a, c2;
                        asm volatile("global_load_dword %0, %2, off sc0 sc1\n\t"
                                     "global_load_dword %1, %3, off sc0 sc1\n\t"
                                     "s_waitcnt vmcnt(0)"
                                     : "=&v"(a), "=&v"(c2)
                                     : "v"(f1), "v"(f2)
                                     : "memory");
                        if (__all(a >= s && c2 >= s)) break;
                        __builtin_amdgcn_s_sleep(1);
                        if (++it > (1 << 17)) { dead = 1; break; }
                    }
                    if (tid == 0) {
                        int val = s;
                        asm volatile("global_store_dword %0, %1, off sc0 sc1"
                                     :: "v"(sup), "v"(val) : "memory");
                    }
                }
            } else if (tid == 0) {
                // single-lane poll of the super-flag
                int it = 0;
                while (true) {
                    int v;
                    asm volatile("global_load_dword %0, %1, off sc0 sc1\n\t"
                                 "s_waitcnt vmcnt(0)"
                                 : "=v"(v) : "v"(sup) : "memory");
                    if (v >= s) break;
                    __builtin_amdgcn_s_sleep(1);
                    if (++it > (1 << 17)) { dead = 1; break; }
                }
            }
        }
        __syncthreads();

        // ---- stage h_{prev} ring slot (128 KB) into LDS via LLC bypass ----
        {
            const char* gbase = (const char*)(ring + (size_t)((s + 1) & 1) * HB)
                                + (size_t)tid * 16;
            char* lbase = (char*)&hsh[0][0] + (size_t)tid * 16;
            float4 tmp[16];
            #pragma unroll
            for (int bi = 0; bi < 2; ++bi) {
                #pragma unroll
                for (int it = 0; it < 16; ++it) {
                    asm volatile("global_load_dwordx4 %0, %1, off sc0 sc1"
                                 : "=v"(tmp[it])
                                 : "v"(gbase + (size_t)(bi * 16 + it) * 4096)
                                 : "memory");
                }
                asm volatile("s_waitcnt vmcnt(0)" ::: "memory");
                #pragma unroll
                for (int it = 0; it < 16; ++it)
                    *(float4*)(lbase + (size_t)(bi * 16 + it) * 4096) = tmp[it];
            }
        }
        __syncthreads();

        // ---- recurrent GEMM part: K = 512 ----
        #pragma unroll 8
        for (int k = 0; k < H; ++k) {
            float hv = hsh[k][b];
            #pragma unroll
            for (int jj = 0; jj < JPW; ++jj)
                acc[jj] = fmaf(hv, whhr[jj][k], acc[jj]);   // weight: scalar load
        }
        #pragma unroll
        for (int jj = 0; jj < JPW; ++jj) zsh[g][jj][b] = acc[jj];
        __syncthreads();

        // ---- gates: thread (jj, b) combines the 4 gate values ----
        {
            const int jj = tid >> 6;
            float iv = zsh[0][jj][b], fv = zsh[1][jj][b];
            float gv = zsh[2][jj][b], ov = zsh[3][jj][b];
            iv = 1.f / (1.f + __expf(-iv));
            fv = 1.f / (1.f + __expf(-fv));
            gv = tanhf(gv);
            ov = 1.f / (1.f + __expf(-ov));
            float c = fv * csh[jj][b] + iv * gv;
            csh[jj][b] = c;
            float hv = ov * tanhf(c);
            // publish h via LLC bypass store (coherent at LLC, no cache ops)
            float* hdst = &ring[(size_t)(s & 1) * HB + (size_t)(j0 + jj) * B + b];
            asm volatile("global_store_dword %0, %1, off sc0 sc1"
                         :: "v"(hdst), "v"(hv) : "memory");
            hs16[(size_t)t * HB + (size_t)(j0 + jj) * B + b] = __float2bfloat16(hv);
        }
        __syncthreads();   // drains vmcnt: all h stores LLC-visible past here
        if (tid == 0) {    // flag publish: relaxed bypass store, own word
            int val = s + 1;
            asm volatile("global_store_dword %0, %1, off sc0 sc1"
                         :: "v"(flg + wslot), "v"(val) : "memory");
        }
    }
}

// ---------------------------------------------------------------------------
// K2: logits -> softmax -> alphabet mix -> normalized sin/cos of torsions.
// ---------------------------------------------------------------------------
__global__ __launch_bounds__(256) void proj_softmax(
    const __hip_bfloat16* __restrict__ hs16_f, const __hip_bfloat16* __restrict__ hs16_b,
    const float* __restrict__ W_lin, const float* __restrict__ b_lin,
    const float* __restrict__ alphabet, float* __restrict__ sp, float* __restrict__ cp)
{
    const int t   = blockIdx.x;
    const int tid = threadIdx.x;
    const int b   = tid & 63;
    const int ug  = __builtin_amdgcn_readfirstlane(tid >> 6);  // 0..3
    constexpr int NU = 15;                                     // 60 = 4*15

    __shared__ float lg[B][LU];
    __shared__ float sa[LU][3], ca[LU][3];
    if (tid < LU) {
        for (int k = 0; k < 3; ++k) {
            float a = alphabet[tid * 3 + k];
            sa[tid][k] = __sinf(a);
            ca[tid][k] = __cosf(a);
        }
    }

    const int u0 = ug * NU;
    float acc[NU];
    #pragma unroll
    for (int i = 0; i < NU; ++i) acc[i] = b_lin[u0 + i];

    const __hip_bfloat16* hf = hs16_f + (size_t)t * HB + b;
    const __hip_bfloat16* hb = hs16_b + (size_t)t * HB + b;
    #pragma unroll 4
    for (int j = 0; j < H; ++j) {
        float hv = __bfloat162float(hf[(size_t)j * B]);
        #pragma unroll
        for (int i = 0; i < NU; ++i)
            acc[i] = fmaf(hv, W_lin[(size_t)(u0 + i) * (2 * H) + j], acc[i]);
    }
    #pragma unroll 4
    for (int j = 0; j < H; ++j) {
        float hv = __bfloat162float(hb[(size_t)j * B]);
        #pragma unroll
        for (int i = 0; i < NU; ++i)
            acc[i] = fmaf(hv, W_lin[(size_t)(u0 + i) * (2 * H) + H + j], acc[i]);
    }
    #pragma unroll
    for (int i = 0; i < NU; ++i) lg[b][u0 + i] = acc[i];
    __syncthreads();

    if (tid < B) {
        float m = -1e30f;
        for (int u = 0; u < LU; ++u) m = fmaxf(m, lg[tid][u]);
        float sv[3] = {0, 0, 0}, cv[3] = {0, 0, 0};
        for (int u = 0; u < LU; ++u) {
            float e = __expf(lg[tid][u] - m);
            for (int k = 0; k < 3; ++k) {
                sv[k] = fmaf(e, sa[u][k], sv[k]);
                cv[k] = fmaf(e, ca[u][k], cv[k]);
            }
        }
        for (int k = 0; k < 3; ++k) {
            float r = rsqrtf(sv[k] * sv[k] + cv[k] * cv[k]);
            sp[((size_t)t * B + tid) * 3 + k] = sv[k] * r;
            cp[((size_t)t * B + tid) * 3 + k] = cv[k] * r;
        }
    }
}

// ---------------------------------------------------------------------------
// K3: sequential NeRF extension. One wave, lane = chain.
// ---------------------------------------------------------------------------
__global__ void geometry(const float* __restrict__ sp, const float* __restrict__ cp,
                         float* __restrict__ out)
{
    const int b = threadIdx.x;   // 64
    const float Rj[3] = {132.868f, 145.801f, 152.326f};
    const float Tj[3] = {2.028f, 2.124f, 1.941f};
    float cT[3], sT[3];
    for (int j = 0; j < 3; ++j) { cT[j] = cosf(Tj[j]); sT[j] = sinf(Tj[j]); }

    for (int r = 0; r < 3; ++r)
        for (int c = 0; c < 3; ++c)
            out[((size_t)r * B + b) * 3 + c] = (r == c) ? 1.f : 0.f;

    float Ax = 1.f, Ay = 0.f, Az = 0.f;
    float Bx = 0.f, By = 1.f, Bz = 0.f;
    float Cx = 0.f, Cy = 0.f, Cz = 1.f;

    for (int t = 0; t < L; ++t) {
        for (int j = 0; j < 3; ++j) {
            float sP = sp[((size_t)t * B + b) * 3 + j];
            float cP = cp[((size_t)t * B + b) * 3 + j];
            float d0 = -Rj[j] * cT[j];
            float d1 =  Rj[j] * cP * sT[j];
            float d2 =  Rj[j] * sP * sT[j];

            float bcx = Cx - Bx, bcy = Cy - By, bcz = Cz - Bz;
            float inv = rsqrtf(bcx * bcx + bcy * bcy + bcz * bcz);
            bcx *= inv; bcy *= inv; bcz *= inv;

            float abx = Bx - Ax, aby = By - Ay, abz = Bz - Az;
            float nx = aby * bcz - abz * bcy;
            float ny = abz * bcx - abx * bcz;
            float nz = abx * bcy - aby * bcx;
            inv = rsqrtf(nx * nx + ny * ny + nz * nz);
            nx *= inv; ny *= inv; nz *= inv;

            float mx = ny * bcz - nz * bcy;
            float my = nz * bcx - nx * bcz;
            float mz = nx * bcy - ny * bcx;

            float Dx = bcx * d0 + mx * d1 + nx * d2 + Cx;
            float Dy = bcy * d0 + my * d1 + ny * d2 + Cy;
            float Dz = bcz * d0 + mz * d1 + nz * d2 + Cz;

            size_t r = 3 + 3 * (size_t)t + j;
            out[(r * B + b) * 3 + 0] = Dx;
            out[(r * B + b) * 3 + 1] = Dy;
            out[(r * B + b) * 3 + 2] = Dz;

            Ax = Bx; Ay = By; Az = Bz;
            Bx = Cx; By = Cy; Bz = Cz;
            Cx = Dx; Cy = Dy; Cz = Dz;
        }
    }
}

// ---------------------------------------------------------------------------
extern "C" void kernel_launch(void* const* d_in, const int* in_sizes, int n_in,
                              void* d_out, int out_size, void* d_ws, size_t ws_size,
                              hipStream_t stream)
{
    const int*   seq      = (const int*)  d_in[0];
    const float* pssm     = (const float*)d_in[1];
    // d_in[2] = length (all full-length)
    const float* embed    = (const float*)d_in[3];
    const float* Wih_f    = (const float*)d_in[4];
    const float* Whh_f    = (const float*)d_in[5];
    const float* bih_f    = (const float*)d_in[6];
    const float* bhh_f    = (const float*)d_in[7];
    const float* Wih_b    = (const float*)d_in[8];
    const float* Whh_b    = (const float*)d_in[9];
    const float* bih_b    = (const float*)d_in[10];
    const float* bhh_b    = (const float*)d_in[11];
    const float* W_lin    = (const float*)d_in[12];
    const float* b_lin    = (const float*)d_in[13];
    const float* alphabet = (const float*)d_in[14];
    float* out = (float*)d_out;

    // workspace layout (~142 MB total)
    char* ws = (char*)d_ws;
    size_t off = 0;
    float* hr    = (float*)(ws + off); off += (size_t)4 * HB * 4;            // 512 KB
    int*   flags = (int*)  (ws + off); off += 4096;                          // flags + supers
    size_t zero_bytes = off;                                                 // one memset covers both
    float* E2    = (float*)(ws + off); off += (size_t)2 * 20 * 2048 * 4;     // 320 KB
    float* pt    = (float*)(ws + off); off += (size_t)L * PSSM * B * 4;      // 5.5 MB
    __hip_bfloat16* hs16_f = (__hip_bfloat16*)(ws + off); off += (size_t)L * HB * 2;  // 64 MB
    __hip_bfloat16* hs16_b = (__hip_bfloat16*)(ws + off); off += (size_t)L * HB * 2;  // 64 MB
    float* sp    = (float*)(ws + off); off += (size_t)L * B * 3 * 4;         // 768 KB
    float* cp    = (float*)(ws + off); off += (size_t)L * B * 3 * 4;         // 768 KB

    hipMemsetAsync(hr, 0, zero_bytes, stream);   // ring slots + flags + supers

    prep_e2<<<dim3(320), dim3(256), 0, stream>>>(Wih_f, Wih_b, embed, E2);
    prep_pssm_t<<<dim3(L), dim3(64), 0, stream>>>(pssm, pt);

    lstm_persistent<<<dim3(2 * NWG_DIR), dim3(256), 0, stream>>>(
        E2, pt, seq, Wih_f, Whh_f, bih_f, bhh_f, Wih_b, Whh_b, bih_b, bhh_b,
        hr, hs16_f, hs16_b, flags);

    proj_softmax<<<dim3(L), dim3(256), 0, stream>>>(hs16_f, hs16_b, W_lin, b_lin,
                                                    alphabet, sp, cp);
    geometry<<<dim3(1), dim3(64), 0, stream>>>(sp, cp, out);
}

// Round 9
// 20655.074 us; speedup vs baseline: 4.5739x; 1.2147x over previous
//
#include <hip/hip_runtime.h>
#include <hip/hip_bf16.h>
#include <math.h>

// Problem constants
constexpr int L    = 1024;
constexpr int B    = 64;
constexpr int H    = 512;
constexpr int ED   = 512;
constexpr int PSSM = 21;
constexpr int DIN  = ED + PSSM;    // 533
constexpr int LU   = 60;
constexpr int HB   = H * B;        // 32768 elements per ring slot
constexpr int NWG_DIR = 32;        // fat MFMA workgroups per direction
constexpr int UPW  = 16;           // hidden units per WG

typedef __attribute__((ext_vector_type(8))) short short8;      // 8 bf16 MFMA frag
typedef __attribute__((ext_vector_type(4))) float f32x4;       // MFMA acc frag
typedef __attribute__((ext_vector_type(4))) unsigned short ushort4v;

__device__ __forceinline__ unsigned bf16_rne(float f) {        // fp32 -> bf16 bits (RNE)
    unsigned u = __float_as_uint(f);
    return (u + 0x7FFFu + ((u >> 16) & 1u)) >> 16;
}
__device__ __forceinline__ float bf16_tof(unsigned us) { return __uint_as_float(us << 16); }

// ---------------------------------------------------------------------------
// P0: E2[dir][sym][col] = embed[sym] . Wih_dir[col][0:512] + bih[col]+bhh[col]
// ---------------------------------------------------------------------------
__global__ __launch_bounds__(256) void prep_e2(
    const float* __restrict__ Wih_f, const float* __restrict__ Wih_b,
    const float* __restrict__ bih_f, const float* __restrict__ bhh_f,
    const float* __restrict__ bih_b, const float* __restrict__ bhh_b,
    const float* __restrict__ embed, float* __restrict__ E2)
{
    int idx  = blockIdx.x * 256 + threadIdx.x;   // 0 .. 81919
    int col  = idx & 2047;
    int rest = idx >> 11;
    int s    = rest % 20;
    int dir  = rest / 20;
    const float* W  = dir ? Wih_b : Wih_f;
    const float* er = embed + (size_t)s * ED;
    const float* wr = W + (size_t)col * DIN;
    float a = 0.f;
    #pragma unroll 8
    for (int k = 0; k < ED; ++k) a = fmaf(er[k], wr[k], a);
    a += (dir ? bih_b : bih_f)[col] + (dir ? bhh_b : bhh_f)[col];
    E2[idx] = a;
}

// ---------------------------------------------------------------------------
// P1: split Whh into bf16 hi/lo pair (3-product split: rel err ~1e-5)
// ---------------------------------------------------------------------------
__global__ __launch_bounds__(256) void prep_whh(
    const float* __restrict__ Whh_f, const float* __restrict__ Whh_b,
    unsigned short* __restrict__ hi, unsigned short* __restrict__ lo)
{
    int idx = blockIdx.x * 256 + threadIdx.x;    // 0 .. 2*2048*512-1
    const int NPD = 2048 * 512;
    float w = (idx < NPD) ? Whh_f[idx] : Whh_b[idx - NPD];
    unsigned h = bf16_rne(w);
    hi[idx] = (unsigned short)h;
    lo[idx] = (unsigned short)bf16_rne(w - bf16_tof(h));
}

// ---------------------------------------------------------------------------
// K1: persistent bidirectional LSTM, MFMA edition. 64 WGs (32/dir), 256 thr.
// WG owns 16 units (64 gate rows); wave q = batch-quarter; gates via
// mfma_f32_16x16x32_bf16 with 3-product hi/lo split, C init = input part.
//
// R9 fix: h is published PRE-SCATTERED into the MFMA A-fragment layout
// (separate hi/lo ushort rings, lin = ((c*4+q)*64 + ((b&15)|(((k>>3)&3)<<4)))*8
// + (k&7)). Consumer staging is a PURE linear 16B copy: asm bypass loads ->
// s_waitcnt (memory clobber) -> raw uint4 LDS stores. No arithmetic touches
// asm-loaded registers before the wait (R8's bug: the compiler hoisted repack
// ALU above the standalone waitcnt since it doesn't model async loads; only
// memory ops are pinned by the clobber).
// ---------------------------------------------------------------------------
__global__ __launch_bounds__(256, 1) void lstm_mfma(
    const float* __restrict__ E2, const float* __restrict__ pssm,
    const int* __restrict__ seq,
    const float* __restrict__ Wih_f, const float* __restrict__ Wih_b,
    const unsigned short* __restrict__ WhhHi, const unsigned short* __restrict__ WhhLo,
    unsigned short* __restrict__ ringHi,       // [2 dir][2 slot][HB] pre-scattered
    unsigned short* __restrict__ ringLo,
    unsigned short* __restrict__ hs16_f, unsigned short* __restrict__ hs16_b,
    int* __restrict__ flags)                   // [dir*64 + wslot]
{
    __shared__ unsigned short ahi[16 * 4 * 64 * 8];   // A-frag hi, 64 KB
    __shared__ unsigned short alo[16 * 4 * 64 * 8];   // A-frag lo, 64 KB

    const int wg    = blockIdx.x;
    const int dir   = wg >> 5;
    const int wslot = wg & 31;
    const int j0    = wslot * UPW;
    const int tid   = threadIdx.x;
    const int l     = tid & 63;
    const int q     = tid >> 6;            // wave = batch-quarter
    const int u     = l & 15;              // unit within WG (B n-index)
    const int kh    = l >> 4;              // quad
    const int m0    = q * 16 + kh * 4;     // base batch index (+r)

    const float* Wih = dir ? Wih_b : Wih_f;
    const float* E2d = E2 + (size_t)dir * 20 * 2048;
    const unsigned short* Whi = WhhHi + (size_t)dir * 2048 * 512;
    const unsigned short* Wlo = WhhLo + (size_t)dir * 2048 * 512;
    unsigned short* rH = ringHi + (size_t)dir * 2 * HB;
    unsigned short* rL = ringLo + (size_t)dir * 2 * HB;
    unsigned short* hs16 = dir ? hs16_b : hs16_f;
    int* flg = flags + dir * 64;

    // per-gate B row element offsets (row-major Whh[row][k])
    size_t brow[4];
    #pragma unroll
    for (int g = 0; g < 4; ++g)
        brow[g] = (size_t)(g * 512 + j0 + u) * 512 + kh * 8;

    // producer scatter constants for k = j0+u
    const int kk    = j0 + u;
    const int pc    = kk >> 5;                    // chunk
    const int pqsel = ((kk >> 3) & 3) << 4;       // quad bits of lane
    const int pj    = kk & 7;                     // element within frag

    float creg[4] = {0.f, 0.f, 0.f, 0.f};
    int dead = 0;

    for (int s = 0; s < L; ++s) {
        const int t = dir ? (L - 1 - s) : s;

        // ---- input part (h-independent): zin[g][r] for batch m0+r ----
        float zin[4][4];
        int sb[4];
        #pragma unroll
        for (int r = 0; r < 4; ++r) sb[r] = seq[t * B + m0 + r];
        #pragma unroll
        for (int g = 0; g < 4; ++g) {
            const int row = g * 512 + j0 + u;
            #pragma unroll
            for (int r = 0; r < 4; ++r) zin[g][r] = E2d[sb[r] * 2048 + row];
        }
        {
            const float* pb = pssm + (size_t)t * B * PSSM;   // [b][21]
            #pragma unroll
            for (int k = 0; k < PSSM; ++k) {
                float p0 = pb[(m0 + 0) * PSSM + k];
                float p1 = pb[(m0 + 1) * PSSM + k];
                float p2 = pb[(m0 + 2) * PSSM + k];
                float p3 = pb[(m0 + 3) * PSSM + k];
                #pragma unroll
                for (int g = 0; g < 4; ++g) {
                    float wv = Wih[(size_t)(g * 512 + j0 + u) * DIN + ED + k];
                    zin[g][0] = fmaf(p0, wv, zin[g][0]);
                    zin[g][1] = fmaf(p1, wv, zin[g][1]);
                    zin[g][2] = fmaf(p2, wv, zin[g][2]);
                    zin[g][3] = fmaf(p3, wv, zin[g][3]);
                }
            }
        }

        // ---- wait: wave 0 polls the 32 per-WG flags (bypass, wait in-asm) ----
        if (s > 0 && tid < 64 && !dead) {
            const int* fp = flg + (l & 31);
            int it = 0;
            while (true) {
                int v;
                asm volatile("global_load_dword %0, %1, off sc0 sc1\n\t"
                             "s_waitcnt vmcnt(0)"
                             : "=v"(v) : "v"(fp) : "memory");
                if (__all(v >= s)) break;
                __builtin_amdgcn_s_sleep(1);
                if (++it > (1 << 17)) { dead = 1; break; }
            }
        }
        __syncthreads();

        // ---- stage h_prev: pure linear copy ring -> LDS (hi then lo) ----
        {
            const int ro = ((s + 1) & 1) * HB;
            #pragma unroll
            for (int a = 0; a < 2; ++a) {
                const unsigned short* src = (a == 0) ? (rH + ro) : (rL + ro);
                unsigned short* dst = (a == 0) ? ahi : alo;
                #pragma unroll
                for (int bi = 0; bi < 2; ++bi) {
                    uint4 va[8];
                    #pragma unroll
                    for (int i = 0; i < 8; ++i) {
                        int idx = (bi * 8 + i) * 256 + tid;   // 16 B units
                        asm volatile("global_load_dwordx4 %0, %1, off sc0 sc1"
                                     : "=&v"(va[i]) : "v"(src + idx * 8) : "memory");
                    }
                    asm volatile("s_waitcnt vmcnt(0)" ::: "memory");
                    #pragma unroll
                    for (int i = 0; i < 8; ++i) {             // pure stores only
                        int idx = (bi * 8 + i) * 256 + tid;
                        *(uint4*)&dst[idx * 8] = va[i];
                    }
                }
            }
        }
        __syncthreads();

        // ---- recurrent GEMM: K=512, 16 chunks, 3-product split ----
        f32x4 acc[4];
        #pragma unroll
        for (int g = 0; g < 4; ++g)
            acc[g] = (f32x4){zin[g][0], zin[g][1], zin[g][2], zin[g][3]};

        #pragma unroll 4
        for (int c = 0; c < 16; ++c) {
            const int ao = ((c * 4 + q) * 64 + l) * 8;
            short8 ah = *(const short8*)&ahi[ao];
            short8 al = *(const short8*)&alo[ao];
            #pragma unroll
            for (int g = 0; g < 4; ++g) {
                short8 bh = *(const short8*)(Whi + brow[g] + c * 32);
                short8 bl = *(const short8*)(Wlo + brow[g] + c * 32);
                acc[g] = __builtin_amdgcn_mfma_f32_16x16x32_bf16(ah, bh, acc[g], 0, 0, 0);
                acc[g] = __builtin_amdgcn_mfma_f32_16x16x32_bf16(ah, bl, acc[g], 0, 0, 0);
                acc[g] = __builtin_amdgcn_mfma_f32_16x16x32_bf16(al, bh, acc[g], 0, 0, 0);
            }
        }

        // ---- gates (in-lane), cell update, publish h pre-scattered ----
        {
            unsigned short* dH = rH + (s & 1) * HB;
            unsigned short* dL = rL + (s & 1) * HB;
            ushort4v hvv;
            #pragma unroll
            for (int r = 0; r < 4; ++r) {
                float iv = acc[0][r], fv = acc[1][r], gv = acc[2][r], ov = acc[3][r];
                iv = 1.f / (1.f + __expf(-iv));
                fv = 1.f / (1.f + __expf(-fv));
                gv = tanhf(gv);
                ov = 1.f / (1.f + __expf(-ov));
                float cc = fv * creg[r] + iv * gv;
                creg[r] = cc;
                float hv = ov * tanhf(cc);
                unsigned hbits = bf16_rne(hv);
                unsigned lbits = bf16_rne(hv - bf16_tof(hbits));
                hvv[r] = (unsigned short)hbits;
                // lin index for (b = m0+r, k = kk) in A-frag layout
                int lin = ((pc * 4 + q) * 64 + ((kh * 4 + r) | pqsel)) * 8 + pj;
                asm volatile("global_store_short %0, %1, off sc0 sc1"
                             :: "v"(dH + lin), "v"(hbits) : "memory");
                asm volatile("global_store_short %0, %1, off sc0 sc1"
                             :: "v"(dL + lin), "v"(lbits) : "memory");
            }
            *(ushort4v*)&hs16[(size_t)t * HB + (size_t)(j0 + u) * B + m0] = hvv;
        }
        __syncthreads();   // each wave drains vmcnt before barrier -> LLC-visible
        if (tid == 0) {
            int val = s + 1;
            asm volatile("global_store_dword %0, %1, off sc0 sc1"
                         :: "v"(flg + wslot), "v"(val) : "memory");
        }
    }
}

// ---------------------------------------------------------------------------
// K2: logits -> softmax -> alphabet mix -> normalized sin/cos of torsions.
// ---------------------------------------------------------------------------
__global__ __launch_bounds__(256) void proj_softmax(
    const __hip_bfloat16* __restrict__ hs16_f, const __hip_bfloat16* __restrict__ hs16_b,
    const float* __restrict__ W_lin, const float* __restrict__ b_lin,
    const float* __restrict__ alphabet, float* __restrict__ sp, float* __restrict__ cp)
{
    const int t   = blockIdx.x;
    const int tid = threadIdx.x;
    const int b   = tid & 63;
    const int ug  = __builtin_amdgcn_readfirstlane(tid >> 6);
    constexpr int NU = 15;

    __shared__ float lg[B][LU];
    __shared__ float sa[LU][3], ca[LU][3];
    if (tid < LU) {
        for (int k = 0; k < 3; ++k) {
            float a = alphabet[tid * 3 + k];
            sa[tid][k] = __sinf(a);
            ca[tid][k] = __cosf(a);
        }
    }

    const int u0 = ug * NU;
    float acc[NU];
    #pragma unroll
    for (int i = 0; i < NU; ++i) acc[i] = b_lin[u0 + i];

    const __hip_bfloat16* hf = hs16_f + (size_t)t * HB + b;
    const __hip_bfloat16* hb = hs16_b + (size_t)t * HB + b;
    #pragma unroll 4
    for (int j = 0; j < H; ++j) {
        float hv = __bfloat162float(hf[(size_t)j * B]);
        #pragma unroll
        for (int i = 0; i < NU; ++i)
            acc[i] = fmaf(hv, W_lin[(size_t)(u0 + i) * (2 * H) + j], acc[i]);
    }
    #pragma unroll 4
    for (int j = 0; j < H; ++j) {
        float hv = __bfloat162float(hb[(size_t)j * B]);
        #pragma unroll
        for (int i = 0; i < NU; ++i)
            acc[i] = fmaf(hv, W_lin[(size_t)(u0 + i) * (2 * H) + H + j], acc[i]);
    }
    #pragma unroll
    for (int i = 0; i < NU; ++i) lg[b][u0 + i] = acc[i];
    __syncthreads();

    if (tid < B) {
        float m = -1e30f;
        for (int u = 0; u < LU; ++u) m = fmaxf(m, lg[tid][u]);
        float sv[3] = {0, 0, 0}, cv[3] = {0, 0, 0};
        for (int u = 0; u < LU; ++u) {
            float e = __expf(lg[tid][u] - m);
            for (int k = 0; k < 3; ++k) {
                sv[k] = fmaf(e, sa[u][k], sv[k]);
                cv[k] = fmaf(e, ca[u][k], cv[k]);
            }
        }
        for (int k = 0; k < 3; ++k) {
            float r = rsqrtf(sv[k] * sv[k] + cv[k] * cv[k]);
            sp[((size_t)t * B + tid) * 3 + k] = sv[k] * r;
            cp[((size_t)t * B + tid) * 3 + k] = cv[k] * r;
        }
    }
}

// ---------------------------------------------------------------------------
// K3: sequential NeRF extension. One wave, lane = chain.
// ---------------------------------------------------------------------------
__global__ void geometry(const float* __restrict__ sp, const float* __restrict__ cp,
                         float* __restrict__ out)
{
    const int b = threadIdx.x;
    const float Rj[3] = {132.868f, 145.801f, 152.326f};
    const float Tj[3] = {2.028f, 2.124f, 1.941f};
    float cT[3], sT[3];
    for (int j = 0; j < 3; ++j) { cT[j] = cosf(Tj[j]); sT[j] = sinf(Tj[j]); }

    for (int r = 0; r < 3; ++r)
        for (int c = 0; c < 3; ++c)
            out[((size_t)r * B + b) * 3 + c] = (r == c) ? 1.f : 0.f;

    float Ax = 1.f, Ay = 0.f, Az = 0.f;
    float Bx = 0.f, By = 1.f, Bz = 0.f;
    float Cx = 0.f, Cy = 0.f, Cz = 1.f;

    for (int t = 0; t < L; ++t) {
        for (int j = 0; j < 3; ++j) {
            float sP = sp[((size_t)t * B + b) * 3 + j];
            float cP = cp[((size_t)t * B + b) * 3 + j];
            float d0 = -Rj[j] * cT[j];
            float d1 =  Rj[j] * cP * sT[j];
            float d2 =  Rj[j] * sP * sT[j];

            float bcx = Cx - Bx, bcy = Cy - By, bcz = Cz - Bz;
            float inv = rsqrtf(bcx * bcx + bcy * bcy + bcz * bcz);
            bcx *= inv; bcy *= inv; bcz *= inv;

            float abx = Bx - Ax, aby = By - Ay, abz = Bz - Az;
            float nx = aby * bcz - abz * bcy;
            float ny = abz * bcx - abx * bcz;
            float nz = abx * bcy - aby * bcx;
            inv = rsqrtf(nx * nx + ny * ny + nz * nz);
            nx *= inv; ny *= inv; nz *= inv;

            float mx = ny * bcz - nz * bcy;
            float my = nz * bcx - nx * bcz;
            float mz = nx * bcy - ny * bcx;

            float Dx = bcx * d0 + mx * d1 + nx * d2 + Cx;
            float Dy = bcy * d0 + my * d1 + ny * d2 + Cy;
            float Dz = bcz * d0 + mz * d1 + nz * d2 + Cz;

            size_t r = 3 + 3 * (size_t)t + j;
            out[(r * B + b) * 3 + 0] = Dx;
            out[(r * B + b) * 3 + 1] = Dy;
            out[(r * B + b) * 3 + 2] = Dz;

            Ax = Bx; Ay = By; Az = Bz;
            Bx = Cx; By = Cy; Bz = Cz;
            Cx = Dx; Cy = Dy; Cz = Dz;
        }
    }
}

// ---------------------------------------------------------------------------
extern "C" void kernel_launch(void* const* d_in, const int* in_sizes, int n_in,
                              void* d_out, int out_size, void* d_ws, size_t ws_size,
                              hipStream_t stream)
{
    const int*   seq      = (const int*)  d_in[0];
    const float* pssm     = (const float*)d_in[1];
    // d_in[2] = length (all full-length)
    const float* embed    = (const float*)d_in[3];
    const float* Wih_f    = (const float*)d_in[4];
    const float* Whh_f    = (const float*)d_in[5];
    const float* bih_f    = (const float*)d_in[6];
    const float* bhh_f    = (const float*)d_in[7];
    const float* Wih_b    = (const float*)d_in[8];
    const float* Whh_b    = (const float*)d_in[9];
    const float* bih_b    = (const float*)d_in[10];
    const float* bhh_b    = (const float*)d_in[11];
    const float* W_lin    = (const float*)d_in[12];
    const float* b_lin    = (const float*)d_in[13];
    const float* alphabet = (const float*)d_in[14];
    float* out = (float*)d_out;

    // workspace layout (~143.5 MB)
    char* ws = (char*)d_ws;
    unsigned short* ringHi = (unsigned short*)ws;                 // 256 KB
    unsigned short* ringLo = (unsigned short*)(ws + 262144);      // 256 KB
    int* flags     = (int*)(ws + 524288);                         // 512 B
    size_t zero_bytes = 524800;
    float* E2      = (float*)(ws + 525312);                       // 320 KB
    unsigned short* WhhHi = (unsigned short*)(ws + 853248);       // 4 MB
    unsigned short* WhhLo = (unsigned short*)(ws + 853248 + 4194304);   // 4 MB
    unsigned short* hs16_f = (unsigned short*)(ws + 853248 + 8388608);  // 64 MB
    unsigned short* hs16_b = (unsigned short*)(ws + 853248 + 8388608 + 67108864);
    // sp/cp overlay E2/Whh region (dead after the LSTM kernel finishes)
    float* sp      = (float*)(ws + 525312);                       // 768 KB
    float* cp      = (float*)(ws + 525312 + 786432);              // 768 KB

    (void)hipMemsetAsync(ringHi, 0, zero_bytes, stream);  // rings + flags

    prep_e2<<<dim3(320), dim3(256), 0, stream>>>(Wih_f, Wih_b, bih_f, bhh_f,
                                                 bih_b, bhh_b, embed, E2);
    prep_whh<<<dim3(8192), dim3(256), 0, stream>>>(Whh_f, Whh_b, WhhHi, WhhLo);

    lstm_mfma<<<dim3(2 * NWG_DIR), dim3(256), 0, stream>>>(
        E2, pssm, seq, Wih_f, Wih_b, WhhHi, WhhLo,
        ringHi, ringLo, hs16_f, hs16_b, flags);

    proj_softmax<<<dim3(L), dim3(256), 0, stream>>>(
        (const __hip_bfloat16*)hs16_f, (const __hip_bfloat16*)hs16_b,
        W_lin, b_lin, alphabet, sp, cp);
    geometry<<<dim3(1), dim3(64), 0, stream>>>(sp, cp, out);
}

// Round 11
// 12374.908 us; speedup vs baseline: 7.6344x; 1.6691x over previous
//
#include <hip/hip_runtime.h>
#include <hip/hip_bf16.h>
#include <hip/hip_fp16.h>
#include <math.h>

// Problem constants
constexpr int L    = 1024;
constexpr int B    = 64;
constexpr int H    = 512;
constexpr int ED   = 512;
constexpr int PSSM = 21;
constexpr int DIN  = ED + PSSM;    // 533
constexpr int LU   = 60;
constexpr int HB   = H * B;        // 32768 elements per ring slot
constexpr int NWG_DIR = 32;        // fat MFMA workgroups per direction
constexpr int UPW  = 16;           // hidden units per WG
constexpr int APAD = 520;          // padded LDS row stride (shorts) for h

typedef __attribute__((ext_vector_type(8))) _Float16 half8;    // MFMA fp16 frag
typedef __attribute__((ext_vector_type(4))) float f32x4;       // MFMA acc frag
typedef __attribute__((ext_vector_type(4))) unsigned short ushort4v;

__device__ __forceinline__ unsigned bf16_rne(float f) {        // fp32 -> bf16 bits
    unsigned u = __float_as_uint(f);
    return (u + 0x7FFFu + ((u >> 16) & 1u)) >> 16;
}

// ---------------------------------------------------------------------------
// P0: E2[dir][sym][col] = embed[sym] . Wih_dir[col][0:512] + bih[col]+bhh[col]
// ---------------------------------------------------------------------------
__global__ __launch_bounds__(256) void prep_e2(
    const float* __restrict__ Wih_f, const float* __restrict__ Wih_b,
    const float* __restrict__ bih_f, const float* __restrict__ bhh_f,
    const float* __restrict__ bih_b, const float* __restrict__ bhh_b,
    const float* __restrict__ embed, float* __restrict__ E2)
{
    int idx  = blockIdx.x * 256 + threadIdx.x;   // 0 .. 81919
    int col  = idx & 2047;
    int rest = idx >> 11;
    int s    = rest % 20;
    int dir  = rest / 20;
    const float* W  = dir ? Wih_b : Wih_f;
    const float* er = embed + (size_t)s * ED;
    const float* wr = W + (size_t)col * DIN;
    float a = 0.f;
    #pragma unroll 8
    for (int k = 0; k < ED; ++k) a = fmaf(er[k], wr[k], a);
    a += (dir ? bih_b : bih_f)[col] + (dir ? bhh_b : bhh_f)[col];
    E2[idx] = a;
}

// ---------------------------------------------------------------------------
// P1: split Whh into fp16 hi/lo pair (2-product fp16 split: W err ~2^-22)
// ---------------------------------------------------------------------------
__global__ __launch_bounds__(256) void prep_whh(
    const float* __restrict__ Whh_f, const float* __restrict__ Whh_b,
    unsigned short* __restrict__ hi, unsigned short* __restrict__ lo)
{
    int idx = blockIdx.x * 256 + threadIdx.x;    // 0 .. 2*2048*512-1
    const int NPD = 2048 * 512;
    float w = (idx < NPD) ? Whh_f[idx] : Whh_b[idx - NPD];
    __half h = __float2half_rn(w);
    __half l2 = __float2half_rn(w - __half2float(h));
    hi[idx] = __half_as_ushort(h);
    lo[idx] = __half_as_ushort(l2);
}

// ---------------------------------------------------------------------------
// K1: persistent bidirectional LSTM, MFMA fp16 edition. 64 WGs (32/dir).
// ~146 KB LDS -> 1 WG/CU, co-resident on 64 CUs. WG owns 16 units (64 gate
// rows); wave q = batch-quarter; mfma_f32_16x16x32_f16, 2 products
// (h x W_hi + h x W_lo), C init = h-independent input part. W_hi in LDS.
// h exchanged as fp16 in NATURAL [b][k] layout via LLC bypass (sc0 sc1):
// staging = pure linear 16B copy (no post-load ALU before waitcnt -> no R8
// hazard); publish = LDS transpose then 512 scalar dword bypass stores
// (uint4 asm INPUTS don't compile on gfx950 -- outputs do; R10 lesson).
// Flags: per-WG own word, wave 0 polls (R5-R9 proven protocol).
// ---------------------------------------------------------------------------
__global__ __launch_bounds__(256, 1) void lstm_mfma(
    const float* __restrict__ E2, const float* __restrict__ pssm,
    const int* __restrict__ seq,
    const float* __restrict__ Wih_f, const float* __restrict__ Wih_b,
    const unsigned short* __restrict__ WhhHi, const unsigned short* __restrict__ WhhLo,
    unsigned short* __restrict__ ring,         // [2dir][2slot][64b][512k] fp16
    unsigned short* __restrict__ hs16_f, unsigned short* __restrict__ hs16_b,
    int* __restrict__ flags)
{
    __shared__ unsigned short hsh[64 * APAD];         // staged h, 66.56 KB
    __shared__ unsigned short bhi[4 * 16 * 64 * 8];   // W_hi B-frags, 64 KB
    __shared__ float wpsh[4][PSSM][16];               // pssm weights, 5.25 KB
    __shared__ float wesh[20][68];                    // E2 slice, 5.3 KB
    __shared__ unsigned short hbuf[64][24];           // publish transpose, 3 KB

    const int wg    = blockIdx.x;
    const int dir   = wg >> 5;
    const int wslot = wg & 31;
    const int j0    = wslot * UPW;
    const int tid   = threadIdx.x;
    const int l     = tid & 63;
    const int q     = tid >> 6;            // wave = batch-quarter
    const int u     = l & 15;              // unit within WG (n index)
    const int kh    = l >> 4;              // quad
    const int m0    = q * 16 + kh * 4;     // base batch (+r)

    const float* Wih = dir ? Wih_b : Wih_f;
    const float* E2d = E2 + (size_t)dir * 20 * 2048;
    const unsigned short* Whi = WhhHi + (size_t)dir * 2048 * 512;
    const unsigned short* Wlo = WhhLo + (size_t)dir * 2048 * 512;
    unsigned short* rbase = ring + (size_t)dir * 2 * HB;
    unsigned short* hs16 = dir ? hs16_b : hs16_f;
    int* flg = flags + dir * 64;

    // ---- one-time LDS fills (plain cached loads) ----
    for (int i = tid; i < 4 * 16 * 64; i += 256) {     // W_hi B-frags
        int l2 = i & 63, c2 = (i >> 6) & 15, g2 = i >> 10;
        int row = g2 * 512 + j0 + (l2 & 15);
        *(uint4*)&bhi[i * 8] =
            *(const uint4*)(Whi + (size_t)row * 512 + c2 * 32 + (l2 >> 4) * 8);
    }
    for (int i = tid; i < 4 * PSSM * 16; i += 256) {   // pssm weight slice
        int uu = i & 15, rem = i >> 4;
        int k = rem % PSSM, g = rem / PSSM;
        wpsh[g][k][uu] = Wih[(size_t)(g * 512 + j0 + uu) * DIN + ED + k];
    }
    for (int i = tid; i < 20 * 64; i += 256) {         // E2 slice
        int sym = i >> 6, col = i & 63;
        wesh[sym][col] = E2d[(size_t)sym * 2048 + (col >> 4) * 512 + j0 + (col & 15)];
    }
    __syncthreads();

    // Wlo row offsets (shorts) per gate
    size_t bloff[4];
    #pragma unroll
    for (int g = 0; g < 4; ++g)
        bloff[g] = (size_t)(g * 512 + j0 + u) * 512 + kh * 8;

    float creg[4] = {0.f, 0.f, 0.f, 0.f};
    int dead = 0;

    for (int s = 0; s < L; ++s) {
        const int t = dir ? (L - 1 - s) : s;

        // ---- input part (h-independent) ----
        float zin[4][4];
        int sb[4];
        #pragma unroll
        for (int r = 0; r < 4; ++r) sb[r] = seq[t * B + m0 + r];
        #pragma unroll
        for (int g = 0; g < 4; ++g)
            #pragma unroll
            for (int r = 0; r < 4; ++r)
                zin[g][r] = wesh[sb[r]][g * 16 + u];
        {
            const float* pb = pssm + (size_t)t * B * PSSM;
            #pragma unroll
            for (int k = 0; k < PSSM; ++k) {
                float p0 = pb[(m0 + 0) * PSSM + k];
                float p1 = pb[(m0 + 1) * PSSM + k];
                float p2 = pb[(m0 + 2) * PSSM + k];
                float p3 = pb[(m0 + 3) * PSSM + k];
                #pragma unroll
                for (int g = 0; g < 4; ++g) {
                    float wv = wpsh[g][k][u];
                    zin[g][0] = fmaf(p0, wv, zin[g][0]);
                    zin[g][1] = fmaf(p1, wv, zin[g][1]);
                    zin[g][2] = fmaf(p2, wv, zin[g][2]);
                    zin[g][3] = fmaf(p3, wv, zin[g][3]);
                }
            }
        }

        // ---- wait: wave 0 polls the 32 per-WG flags ----
        if (s > 0 && tid < 64 && !dead) {
            const int* fp = flg + (l & 31);
            int it = 0;
            while (true) {
                int v;
                asm volatile("global_load_dword %0, %1, off sc0 sc1\n\t"
                             "s_waitcnt vmcnt(0)"
                             : "=v"(v) : "v"(fp) : "memory");
                if (__all(v >= s)) break;
                __builtin_amdgcn_s_sleep(1);
                if (++it > (1 << 17)) { dead = 1; break; }
            }
        }
        __syncthreads();

        // ---- stage h_prev (64 KB fp16) -> padded LDS, pure linear copy ----
        {
            const unsigned short* src = rbase + ((s + 1) & 1) * HB;
            #pragma unroll
            for (int bi = 0; bi < 2; ++bi) {
                uint4 va[8];
                #pragma unroll
                for (int i = 0; i < 8; ++i) {
                    int idx = (bi * 8 + i) * 256 + tid;    // 16B units
                    asm volatile("global_load_dwordx4 %0, %1, off sc0 sc1"
                                 : "=&v"(va[i]) : "v"(src + idx * 8) : "memory");
                }
                asm volatile("s_waitcnt vmcnt(0)" ::: "memory");
                #pragma unroll
                for (int i = 0; i < 8; ++i) {              // pure stores only
                    int idx = (bi * 8 + i) * 256 + tid;
                    int bb = idx >> 6, cu = idx & 63;
                    *(uint4*)&hsh[bb * APAD + cu * 8] = va[i];
                }
            }
        }
        __syncthreads();

        // ---- recurrent GEMM: K=512, 16 chunks, 2 fp16 products ----
        f32x4 acc[4];
        #pragma unroll
        for (int g = 0; g < 4; ++g)
            acc[g] = (f32x4){zin[g][0], zin[g][1], zin[g][2], zin[g][3]};

        #pragma unroll 4
        for (int c = 0; c < 16; ++c) {
            half8 ah = *(const half8*)&hsh[(q * 16 + u) * APAD + c * 32 + kh * 8];
            #pragma unroll
            for (int g = 0; g < 4; ++g) {
                half8 bh = *(const half8*)&bhi[((g * 16 + c) * 64 + l) * 8];
                half8 bl = *(const half8*)(Wlo + bloff[g] + c * 32);
                acc[g] = __builtin_amdgcn_mfma_f32_16x16x32_f16(ah, bh, acc[g], 0, 0, 0);
                acc[g] = __builtin_amdgcn_mfma_f32_16x16x32_f16(ah, bl, acc[g], 0, 0, 0);
            }
        }

        // ---- gates (in-lane), cell update, h -> LDS transpose buffer ----
        {
            ushort4v hvv;
            #pragma unroll
            for (int r = 0; r < 4; ++r) {
                float iv = acc[0][r], fv = acc[1][r], gv = acc[2][r], ov = acc[3][r];
                iv = 1.f / (1.f + __expf(-iv));
                fv = 1.f / (1.f + __expf(-fv));
                gv = tanhf(gv);
                ov = 1.f / (1.f + __expf(-ov));
                float cc = fv * creg[r] + iv * gv;
                creg[r] = cc;
                float hv = ov * tanhf(cc);
                hbuf[m0 + r][u] = __half_as_ushort(__float2half_rn(hv));
                hvv[r] = (unsigned short)bf16_rne(hv);    // bf16 history
            }
            *(ushort4v*)&hs16[(size_t)t * HB + (size_t)(j0 + u) * B + m0] = hvv;
        }
        __syncthreads();

        // ---- publish: 256 threads x 2 scalar dword bypass stores ----
        {
            int bb = tid >> 2, g4 = (tid & 3) * 4;        // 4 units per thread
            unsigned v0 = *(const unsigned*)&hbuf[bb][g4];
            unsigned v1 = *(const unsigned*)&hbuf[bb][g4 + 2];
            unsigned short* d = rbase + (s & 1) * HB + bb * 512 + j0 + g4;
            asm volatile("global_store_dword %0, %1, off sc0 sc1"
                         :: "v"(d), "v"(v0) : "memory");
            asm volatile("global_store_dword %0, %1, off sc0 sc1"
                         :: "v"(d + 2), "v"(v1) : "memory");
        }
        __syncthreads();   // waves drain vmcnt before barrier -> LLC-visible
        if (tid == 0) {
            int val = s + 1;
            asm volatile("global_store_dword %0, %1, off sc0 sc1"
                         :: "v"(flg + wslot), "v"(val) : "memory");
        }
    }
}

// ---------------------------------------------------------------------------
// K2: logits -> softmax -> alphabet mix -> normalized sin/cos of torsions.
// ---------------------------------------------------------------------------
__global__ __launch_bounds__(256) void proj_softmax(
    const __hip_bfloat16* __restrict__ hs16_f, const __hip_bfloat16* __restrict__ hs16_b,
    const float* __restrict__ W_lin, const float* __restrict__ b_lin,
    const float* __restrict__ alphabet, float* __restrict__ sp, float* __restrict__ cp)
{
    const int t   = blockIdx.x;
    const int tid = threadIdx.x;
    const int b   = tid & 63;
    const int ug  = __builtin_amdgcn_readfirstlane(tid >> 6);
    constexpr int NU = 15;

    __shared__ float lg[B][LU];
    __shared__ float sa[LU][3], ca[LU][3];
    if (tid < LU) {
        for (int k = 0; k < 3; ++k) {
            float a = alphabet[tid * 3 + k];
            sa[tid][k] = __sinf(a);
            ca[tid][k] = __cosf(a);
        }
    }

    const int u0 = ug * NU;
    float acc[NU];
    #pragma unroll
    for (int i = 0; i < NU; ++i) acc[i] = b_lin[u0 + i];

    const __hip_bfloat16* hf = hs16_f + (size_t)t * HB + b;
    const __hip_bfloat16* hb = hs16_b + (size_t)t * HB + b;
    #pragma unroll 4
    for (int j = 0; j < H; ++j) {
        float hv = __bfloat162float(hf[(size_t)j * B]);
        #pragma unroll
        for (int i = 0; i < NU; ++i)
            acc[i] = fmaf(hv, W_lin[(size_t)(u0 + i) * (2 * H) + j], acc[i]);
    }
    #pragma unroll 4
    for (int j = 0; j < H; ++j) {
        float hv = __bfloat162float(hb[(size_t)j * B]);
        #pragma unroll
        for (int i = 0; i < NU; ++i)
            acc[i] = fmaf(hv, W_lin[(size_t)(u0 + i) * (2 * H) + H + j], acc[i]);
    }
    #pragma unroll
    for (int i = 0; i < NU; ++i) lg[b][u0 + i] = acc[i];
    __syncthreads();

    if (tid < B) {
        float m = -1e30f;
        for (int u = 0; u < LU; ++u) m = fmaxf(m, lg[tid][u]);
        float sv[3] = {0, 0, 0}, cv[3] = {0, 0, 0};
        for (int u = 0; u < LU; ++u) {
            float e = __expf(lg[tid][u] - m);
            for (int k = 0; k < 3; ++k) {
                sv[k] = fmaf(e, sa[u][k], sv[k]);
                cv[k] = fmaf(e, ca[u][k], cv[k]);
            }
        }
        for (int k = 0; k < 3; ++k) {
            float r = rsqrtf(sv[k] * sv[k] + cv[k] * cv[k]);
            sp[((size_t)t * B + tid) * 3 + k] = sv[k] * r;
            cp[((size_t)t * B + tid) * 3 + k] = cv[k] * r;
        }
    }
}

// ---------------------------------------------------------------------------
// K3: sequential NeRF extension. One wave, lane = chain.
// ---------------------------------------------------------------------------
__global__ void geometry(const float* __restrict__ sp, const float* __restrict__ cp,
                         float* __restrict__ out)
{
    const int b = threadIdx.x;
    const float Rj[3] = {132.868f, 145.801f, 152.326f};
    const float Tj[3] = {2.028f, 2.124f, 1.941f};
    float cT[3], sT[3];
    for (int j = 0; j < 3; ++j) { cT[j] = cosf(Tj[j]); sT[j] = sinf(Tj[j]); }

    for (int r = 0; r < 3; ++r)
        for (int c = 0; c < 3; ++c)
            out[((size_t)r * B + b) * 3 + c] = (r == c) ? 1.f : 0.f;

    float Ax = 1.f, Ay = 0.f, Az = 0.f;
    float Bx = 0.f, By = 1.f, Bz = 0.f;
    float Cx = 0.f, Cy = 0.f, Cz = 1.f;

    for (int t = 0; t < L; ++t) {
        for (int j = 0; j < 3; ++j) {
            float sP = sp[((size_t)t * B + b) * 3 + j];
            float cP = cp[((size_t)t * B + b) * 3 + j];
            float d0 = -Rj[j] * cT[j];
            float d1 =  Rj[j] * cP * sT[j];
            float d2 =  Rj[j] * sP * sT[j];

            float bcx = Cx - Bx, bcy = Cy - By, bcz = Cz - Bz;
            float inv = rsqrtf(bcx * bcx + bcy * bcy + bcz * bcz);
            bcx *= inv; bcy *= inv; bcz *= inv;

            float abx = Bx - Ax, aby = By - Ay, abz = Bz - Az;
            float nx = aby * bcz - abz * bcy;
            float ny = abz * bcx - abx * bcz;
            float nz = abx * bcy - aby * bcx;
            inv = rsqrtf(nx * nx + ny * ny + nz * nz);
            nx *= inv; ny *= inv; nz *= inv;

            float mx = ny * bcz - nz * bcy;
            float my = nz * bcx - nx * bcz;
            float mz = nx * bcy - ny * bcx;

            float Dx = bcx * d0 + mx * d1 + nx * d2 + Cx;
            float Dy = bcy * d0 + my * d1 + ny * d2 + Cy;
            float Dz = bcz * d0 + mz * d1 + nz * d2 + Cz;

            size_t r = 3 + 3 * (size_t)t + j;
            out[(r * B + b) * 3 + 0] = Dx;
            out[(r * B + b) * 3 + 1] = Dy;
            out[(r * B + b) * 3 + 2] = Dz;

            Ax = Bx; Ay = By; Az = Bz;
            Bx = Cx; By = Cy; Bz = Cz;
            Cx = Dx; Cy = Dy; Cz = Dz;
        }
    }
}

// ---------------------------------------------------------------------------
extern "C" void kernel_launch(void* const* d_in, const int* in_sizes, int n_in,
                              void* d_out, int out_size, void* d_ws, size_t ws_size,
                              hipStream_t stream)
{
    const int*   seq      = (const int*)  d_in[0];
    const float* pssm     = (const float*)d_in[1];
    // d_in[2] = length (all full-length)
    const float* embed    = (const float*)d_in[3];
    const float* Wih_f    = (const float*)d_in[4];
    const float* Whh_f    = (const float*)d_in[5];
    const float* bih_f    = (const float*)d_in[6];
    const float* bhh_f    = (const float*)d_in[7];
    const float* Wih_b    = (const float*)d_in[8];
    const float* Whh_b    = (const float*)d_in[9];
    const float* bih_b    = (const float*)d_in[10];
    const float* bhh_b    = (const float*)d_in[11];
    const float* W_lin    = (const float*)d_in[12];
    const float* b_lin    = (const float*)d_in[13];
    const float* alphabet = (const float*)d_in[14];
    float* out = (float*)d_out;

    // workspace layout (~143 MB)
    char* ws = (char*)d_ws;
    unsigned short* ring = (unsigned short*)ws;                   // 256 KB
    int* flags     = (int*)(ws + 262144);                         // 512 B
    size_t zero_bytes = 262656;
    float* E2      = (float*)(ws + 263168);                       // 320 KB
    unsigned short* WhhHi = (unsigned short*)(ws + 591104);       // 4 MB
    unsigned short* WhhLo = (unsigned short*)(ws + 591104 + 4194304);   // 4 MB
    unsigned short* hs16_f = (unsigned short*)(ws + 591104 + 8388608);  // 64 MB
    unsigned short* hs16_b = (unsigned short*)(ws + 591104 + 8388608 + 67108864);
    // sp/cp overlay E2/Whh region (dead after the LSTM kernel finishes)
    float* sp      = (float*)(ws + 263168);                       // 768 KB
    float* cp      = (float*)(ws + 263168 + 786432);              // 768 KB

    (void)hipMemsetAsync(ring, 0, zero_bytes, stream);   // ring + flags

    prep_e2<<<dim3(320), dim3(256), 0, stream>>>(Wih_f, Wih_b, bih_f, bhh_f,
                                                 bih_b, bhh_b, embed, E2);
    prep_whh<<<dim3(8192), dim3(256), 0, stream>>>(Whh_f, Whh_b, WhhHi, WhhLo);

    lstm_mfma<<<dim3(2 * NWG_DIR), dim3(256), 0, stream>>>(
        E2, pssm, seq, Wih_f, Wih_b, WhhHi, WhhLo,
        ring, hs16_f, hs16_b, flags);

    proj_softmax<<<dim3(L), dim3(256), 0, stream>>>(
        (const __hip_bfloat16*)hs16_f, (const __hip_bfloat16*)hs16_b,
        W_lin, b_lin, alphabet, sp, cp);
    geometry<<<dim3(1), dim3(64), 0, stream>>>(sp, cp, out);
}